// Round 6
// baseline (433.517 us; speedup 1.0000x reference)
//
#include <hip/hip_runtime.h>

typedef unsigned short u16;
typedef unsigned int u32;

using short8  = __attribute__((ext_vector_type(8))) short;
using f32x4   = __attribute__((ext_vector_type(4))) float;
using float4v = __attribute__((ext_vector_type(4))) float;
using uint2v  = __attribute__((ext_vector_type(2))) unsigned int;

#define LOG2E 1.44269504088896340736f

// X1 row (per batch): [h1 0:128 | pad] (u16)
#define X1S 136
// H2 row: [h2 0:64 | pad]
#define H2S 72
#define DBS 40
// XCH row stride: 8 steps * 40 + 8 pad (656 B: 16B-aligned, bank-stride 4)
#define XCS 328

__device__ __forceinline__ u16 f2bf(float f) {
  u32 u = __float_as_uint(f);
  return (u16)((u + 0x7FFFu + ((u >> 16) & 1u)) >> 16);
}
// packed f32x2 -> bf16x2, RNE (same rounding as f2bf), 1 instr
__device__ __forceinline__ u32 pkbf(float a, float b) {
  u32 r;
  asm("v_cvt_pk_bf16_f32 %0, %1, %2" : "=v"(r) : "v"(a), "v"(b));
  return r;
}
__device__ __forceinline__ float sigm(float x) {
  return __builtin_amdgcn_rcpf(1.0f + __builtin_amdgcn_exp2f(-LOG2E * x));
}
__device__ __forceinline__ float tanh_(float x) {
  return 1.0f - 2.0f * __builtin_amdgcn_rcpf(1.0f + __builtin_amdgcn_exp2f(2.0f * LOG2E * x));
}
__device__ __forceinline__ f32x4 mfma_(short8 a, short8 b, f32x4 c) {
  return __builtin_amdgcn_mfma_f32_16x16x32_bf16(a, b, c, 0, 0, 0);
}
__device__ __forceinline__ float cellr(float gi, float gf, float gg, float go, float& cr) {
  const float ig = sigm(gi), fg = sigm(gf), g = tanh_(gg), og = sigm(go);
  const float cn = fg * cr + ig * g;
  cr = cn;
  return og * tanh_(cn);
}

// R17 = R16 + all steady-state weights in REGISTERS (was: re-read from LDS
// every step -> 96 of 160 ds_read_b128/step were static weights; LDS pipe
// ~1300-1900 cyc/step was on par with VALU issue).
//  - wu[24] (96 VGPR), role-overlaid to keep allocation under the
//    3-waves/SIMD cap (170):
//      L1 waves: wu[ty*4+kc] = Whh1 frags, wu[16+ty]       = Wih1 x-frags
//      L2 waves: wu[ty*4+kc] = Wih2 frags, wu[16+ty*2+kc]  = Whh2 frags
//  - W1xF / W2F LDS arrays + fills deleted: LDS 136 KB -> 40 KB,
//    per-step LDS reads 160 -> 64 b128
__global__ __launch_bounds__(768, 3) void spc_lstm(
    const float* __restrict__ xh,   const float* __restrict__ xfr,
    const float* __restrict__ Wih1, const float* __restrict__ Whh1,
    const float* __restrict__ bih1, const float* __restrict__ bhh1,
    const float* __restrict__ Wih2, const float* __restrict__ Whh2,
    const float* __restrict__ bih2, const float* __restrict__ bhh2,
    const float* __restrict__ Wd,   const float* __restrict__ bd,
    const float* __restrict__ Wf,   const float* __restrict__ bfv,
    const float* __restrict__ ob,   float* __restrict__ out)
{
  __shared__ __align__(16) u16 X1[2][16 * X1S];   //  8704 B
  __shared__ __align__(16) u16 H2B[2][16 * H2S];  //  4608 B
  __shared__ __align__(16) u16 DB[16 * DBS];      //  1280 B
  __shared__ __align__(16) u16 WdF[4 * 512];      //  4096 B
  __shared__ __align__(16) u16 WfF[512];          //  1024 B
  __shared__ __align__(16) u16 XCH[2][16 * XCS];  // 20992 B x chunk ring
  // total ~40 KB

  const int tid = threadIdx.x;
  const int wv  = tid >> 6;          // 0..11
  const int l   = tid & 63;
  const int c   = l & 15;
  const int q   = l >> 4;
  const int bb  = blockIdx.x << 4;
  const bool isL1 = (wv < 8);
  const bool isL2 = !isL1;
  const int  wv8  = wv - 8;

  // hoisted lane-offsets (u16 indices)
  const int cX1 = c * X1S, cH2 = c * H2S, cXC = c * XCS;
  const int l8 = l * 8, q8 = q * 8, q4 = q * 4;
  const int u2  = wv * 16 + c;       // L1 unit col
  const int u2b = wv8 * 16 + c;      // L2 unit col

  // Role-overlaid persistent weight registers (96 VGPR):
  //  L1: wu[ty*4+kc]=Whh1, wu[16+ty]=Wih1-x (q>=2 lanes zero)
  //  L2: wu[ty*4+kc]=Wih2, wu[16+ty*2+kc]=Whh2
  short8 wu[24];
  float  br[4];
  float  cs0 = 0.f, cs1 = 0.f, cs2 = 0.f, cs3 = 0.f;

  // ---- zero activation + chunk LDS ----
  for (int i = tid; i < 2 * 16 * X1S; i += 768) ((u16*)X1)[i] = 0;
  for (int i = tid; i < 2 * 16 * H2S; i += 768) ((u16*)H2B)[i] = 0;
  for (int i = tid; i < 16 * DBS; i += 768) DB[i] = 0;
  for (int i = tid; i < 2 * 16 * XCS; i += 768) ((u16*)XCH)[i] = 0;
  __syncthreads();

  // ---- decoder-head weight LDS (cold path only) ----
  for (int i = tid; i < 4 * 512; i += 768) {          // Wd tiles (ww, kc2)
    const int tix = i >> 9, e = i & 511, k = e >> 4, n = e & 15;
    const int ww = tix >> 1, kc2 = tix & 1;
    WdF[tix * 512 + ((k >> 3) * 16 + n) * 8 + (k & 7)] =
        f2bf(Wd[(ww * 16 + n) * 64 + kc2 * 32 + k]);
  }
  {                                                   // Wf (zeros n>=2)
    const int k = tid >> 4, n = tid & 15;
    if (tid < 512)
      WfF[((k >> 3) * 16 + n) * 8 + (k & 7)] = (n < 2) ? f2bf(Wf[n * 32 + k]) : (u16)0;
  }

  // ---- chunk 0 load (L2 waves): steps 0-7 into XCH[0] ----
  if (isL2) {
    const int i0 = tid - 512;
    #pragma unroll
    for (int p = 0; p < 2; p++) {
      const int idx = i0 + p * 256;
      const int r = idx >> 5, rem = idx & 31, st = rem >> 2, hf = rem & 3;
      const float4v v = *(const float4v*)&xh[(bb + r) * 3200 + st * 16 + hf * 4];
      *(uint2v*)&XCH[0][r * XCS + st * 40 + hf * 4] =
          (uint2v){pkbf(v[0], v[1]), pkbf(v[2], v[3])};
    }
  }

  // ---- register weights / biases (role-overlaid) ----
  if (isL1) {
    #pragma unroll
    for (int ty = 0; ty < 4; ty++) {
      const int g = ty * 128 + wv * 16 + c;
      br[ty] = bih1[g] + bhh1[g];
      #pragma unroll
      for (int kc = 0; kc < 4; kc++) {
        short8 v;
        #pragma unroll
        for (int j = 0; j < 8; j++)
          v[j] = (short)f2bf(Whh1[g * 128 + kc * 32 + q * 8 + j]);
        wu[ty * 4 + kc] = v;
      }
      short8 vx;                                      // Wih1 x-frag: k = q*8+j
      #pragma unroll
      for (int j = 0; j < 8; j++)
        vx[j] = (q < 2) ? (short)f2bf(Wih1[g * 16 + q * 8 + j]) : (short)0;
      wu[16 + ty] = vx;
    }
  } else {
    #pragma unroll
    for (int ty = 0; ty < 4; ty++) {
      const int g2 = ty * 64 + wv8 * 16 + c;
      br[ty] = bih2[g2] + bhh2[g2];
      #pragma unroll
      for (int kc = 0; kc < 4; kc++) {                // Wih2 frags (k = q*8+j + 32*kc)
        short8 v;
        #pragma unroll
        for (int j = 0; j < 8; j++)
          v[j] = (short)f2bf(Wih2[g2 * 128 + kc * 32 + q * 8 + j]);
        wu[ty * 4 + kc] = v;
      }
      #pragma unroll
      for (int kc = 0; kc < 2; kc++) {                // Whh2 frags
        short8 v;
        #pragma unroll
        for (int j = 0; j < 8; j++)
          v[j] = (short)f2bf(Whh2[g2 * 64 + kc * 32 + q * 8 + j]);
        wu[16 + ty * 2 + kc] = v;
      }
    }
  }
  float bdr0 = 0.f, bdr1 = 0.f, bfr = 0.f;
  if (wv == 8) {
    bdr0 = bd[c];
    bdr1 = bd[16 + c];
    if (c < 2) bfr = bfv[c] + ob[c];
  }
  __syncthreads();

// ---- step macros (PAR/SLOT may be constants (hot) or runtime (decoder)) ----
#define L2_STEP(PAR)                                                          \
  do { if (isL2) {                                                            \
    const u16* Xc_ = X1[(PAR)];                                               \
    const u16* Hp_ = H2B[(PAR)];                                              \
    u16* Hd_ = H2B[(PAR) ^ 1];                                                \
    f32x4 a0 = (f32x4){br[0], br[0], br[0], br[0]};                           \
    f32x4 a1 = (f32x4){br[1], br[1], br[1], br[1]};                           \
    f32x4 a2 = (f32x4){br[2], br[2], br[2], br[2]};                           \
    f32x4 a3 = (f32x4){br[3], br[3], br[3], br[3]};                           \
    __builtin_amdgcn_s_setprio(1);                                            \
    _Pragma("unroll") for (int kc = 0; kc < 4; kc++) {                        \
      const short8 fh = *(const short8*)&Xc_[cX1 + kc * 32 + q8];             \
      a0 = mfma_(fh, wu[0 * 4 + kc], a0);                                     \
      a1 = mfma_(fh, wu[1 * 4 + kc], a1);                                     \
      a2 = mfma_(fh, wu[2 * 4 + kc], a2);                                     \
      a3 = mfma_(fh, wu[3 * 4 + kc], a3);                                     \
    }                                                                         \
    _Pragma("unroll") for (int kc = 0; kc < 2; kc++) {                        \
      const short8 hh = *(const short8*)&Hp_[cH2 + kc * 32 + q8];             \
      a0 = mfma_(hh, wu[16 + 0 * 2 + kc], a0);                                \
      a1 = mfma_(hh, wu[16 + 1 * 2 + kc], a1);                                \
      a2 = mfma_(hh, wu[16 + 2 * 2 + kc], a2);                                \
      a3 = mfma_(hh, wu[16 + 3 * 2 + kc], a3);                                \
    }                                                                         \
    __builtin_amdgcn_s_setprio(0);                                            \
    const float h0_ = cellr(a0[0], a1[0], a2[0], a3[0], cs0);                 \
    const float h1_ = cellr(a0[1], a1[1], a2[1], a3[1], cs1);                 \
    const float h2_ = cellr(a0[2], a1[2], a2[2], a3[2], cs2);                 \
    const float h3_ = cellr(a0[3], a1[3], a2[3], a3[3], cs3);                 \
    const u32 p01 = pkbf(h0_, h1_), p23 = pkbf(h2_, h3_);                     \
    Hd_[(q4 + 0) * H2S + u2b] = (u16)p01;                                     \
    Hd_[(q4 + 1) * H2S + u2b] = (u16)(p01 >> 16);                             \
    Hd_[(q4 + 2) * H2S + u2b] = (u16)p23;                                     \
    Hd_[(q4 + 3) * H2S + u2b] = (u16)(p23 >> 16);                             \
  } } while (0)

#define L1_STEP(PAR, SLOT, XRP)                                               \
  do { if (isL1) {                                                            \
    const u16* Xc_ = X1[(PAR)];                                               \
    u16* Xn_ = X1[(PAR) ^ 1];                                                 \
    f32x4 a0 = (f32x4){br[0], br[0], br[0], br[0]};                           \
    f32x4 a1 = (f32x4){br[1], br[1], br[1], br[1]};                           \
    f32x4 a2 = (f32x4){br[2], br[2], br[2], br[2]};                           \
    f32x4 a3 = (f32x4){br[3], br[3], br[3], br[3]};                           \
    __builtin_amdgcn_s_setprio(1);                                            \
    _Pragma("unroll") for (int kc = 0; kc < 4; kc++) {                        \
      const short8 ah = *(const short8*)&Xc_[cX1 + kc * 32 + q8];             \
      a0 = mfma_(ah, wu[0 * 4 + kc], a0);                                     \
      a1 = mfma_(ah, wu[1 * 4 + kc], a1);                                     \
      a2 = mfma_(ah, wu[2 * 4 + kc], a2);                                     \
      a3 = mfma_(ah, wu[3 * 4 + kc], a3);                                     \
    }                                                                         \
    {                                                                         \
      const short8 ax = *(const short8*)&(XRP)[cXC + (SLOT) * 40 + q8];       \
      a0 = mfma_(ax, wu[16 + 0], a0);                                         \
      a1 = mfma_(ax, wu[16 + 1], a1);                                         \
      a2 = mfma_(ax, wu[16 + 2], a2);                                         \
      a3 = mfma_(ax, wu[16 + 3], a3);                                         \
    }                                                                         \
    __builtin_amdgcn_s_setprio(0);                                            \
    const float h0_ = cellr(a0[0], a1[0], a2[0], a3[0], cs0);                 \
    const float h1_ = cellr(a0[1], a1[1], a2[1], a3[1], cs1);                 \
    const float h2_ = cellr(a0[2], a1[2], a2[2], a3[2], cs2);                 \
    const float h3_ = cellr(a0[3], a1[3], a2[3], a3[3], cs3);                 \
    const u32 p01 = pkbf(h0_, h1_), p23 = pkbf(h2_, h3_);                     \
    Xn_[(q4 + 0) * X1S + u2] = (u16)p01;                                      \
    Xn_[(q4 + 1) * X1S + u2] = (u16)(p01 >> 16);                              \
    Xn_[(q4 + 2) * X1S + u2] = (u16)p23;                                      \
    Xn_[(q4 + 3) * X1S + u2] = (u16)(p23 >> 16);                              \
  } } while (0)

  // ---- encoder: 25 chunks x 8 unrolled steps (t = 8m + j, parity = j&1) ----
  #pragma unroll 1
  for (int m = 0; m < 25; ++m) {
    const u16* xr = XCH[m & 1];
    u16* xw = XCH[(m & 1) ^ 1];

    // j = 0: issue next-chunk loads early (hide HBM under L2 MFMAs)
    float4v stg0, stg1;
    const bool doLd = isL2 && (m < 24);
    const int i0 = tid - 512;
    const int r0 = i0 >> 5, rem0 = i0 & 31, st0 = rem0 >> 2, hf0 = rem0 & 3;
    const int i1 = i0 + 256;
    const int r1 = i1 >> 5, rem1 = i1 & 31, st1 = rem1 >> 2, hf1 = rem1 & 3;
    if (doLd) {
      const int t0 = (m + 1) << 3;
      stg0 = *(const float4v*)&xh[(bb + r0) * 3200 + (t0 + st0) * 16 + hf0 * 4];
      stg1 = *(const float4v*)&xh[(bb + r1) * 3200 + (t0 + st1) * 16 + hf1 * 4];
    }
    if (m) L2_STEP(0);
    if (doLd) {
      *(uint2v*)&xw[r0 * XCS + st0 * 40 + hf0 * 4] =
          (uint2v){pkbf(stg0[0], stg0[1]), pkbf(stg0[2], stg0[3])};
      *(uint2v*)&xw[r1 * XCS + st1 * 40 + hf1 * 4] =
          (uint2v){pkbf(stg1[0], stg1[1]), pkbf(stg1[2], stg1[3])};
    } else if (isL2 && m == 24) {                     // decoder chunk 25 (xfr)
      for (int e = i0; e < 16 * 8 * 14; e += 256) {
        const int r = e / 112, rem2 = e % 112, st = rem2 / 14, f = rem2 % 14;
        xw[r * XCS + st * 40 + f] = f2bf(xfr[(bb + r) * 280 + st * 14 + f]);
      }
      if (i0 < 32) {                                  // s=0 feats 14,15
        const int r = i0 >> 1, f = 14 + (i0 & 1);
        xw[r * XCS + f] = f2bf(xh[(bb + r) * 3200 + 199 * 16 + f]);
      }
    }
    L1_STEP(0, 0, xr);
    __syncthreads();

    L2_STEP(1); L1_STEP(1, 1, xr); __syncthreads();
    L2_STEP(0); L1_STEP(0, 2, xr); __syncthreads();
    L2_STEP(1); L1_STEP(1, 3, xr); __syncthreads();
    L2_STEP(0); L1_STEP(0, 4, xr); __syncthreads();
    L2_STEP(1); L1_STEP(1, 5, xr); __syncthreads();
    L2_STEP(0); L1_STEP(0, 6, xr); __syncthreads();
    L2_STEP(1); L1_STEP(1, 7, xr); __syncthreads();
  }

  // ---- t = 200 (first decoder input, no head yet) + load chunk 26 ----
  {
    L2_STEP(0);
    if (isL2) {                                       // chunk 26 -> XCH[0]
      u16* dst = (u16*)XCH[0];
      const int i0 = tid - 512;
      for (int e = i0; e < 16 * 8 * 14; e += 256) {
        const int r = e / 112, rem2 = e % 112, st = rem2 / 14, f = rem2 % 14;
        dst[r * XCS + st * 40 + f] = f2bf(xfr[(bb + r) * 280 + (8 + st) * 14 + f]);
      }
    }
    L1_STEP(0, 0, XCH[1]);
    __syncthreads();
  }

  // ---- decoder: t = 201..220 (cold path, rolled) ----
  #pragma unroll 1
  for (int t = 201; t <= 220; ++t) {
    L2_STEP(t & 1);
    if (isL2 && t == 208) {                           // chunk 27 -> XCH[1]
      u16* dst = (u16*)XCH[1];
      const int i0 = tid - 512;
      for (int e = i0; e < 16 * 8 * 14; e += 256) {
        const int r = e / 112, rem2 = e % 112, st = rem2 / 14, f = rem2 % 14;
        if (16 + st < 20)
          dst[r * XCS + st * 40 + f] = f2bf(xfr[(bb + r) * 280 + (16 + st) * 14 + f]);
      }
    }
    __syncthreads();                                  // #1: h2(t-1) visible
    if (wv == 8) {
      u16* Hd_ = H2B[(t & 1) ^ 1];
      f32x4 d0 = (f32x4){bdr0, bdr0, bdr0, bdr0};
      f32x4 d1 = (f32x4){bdr1, bdr1, bdr1, bdr1};
      #pragma unroll
      for (int kc = 0; kc < 2; kc++) {
        const short8 ad = *(const short8*)&Hd_[cH2 + kc * 32 + q8];
        d0 = mfma_(ad, *(const short8*)&WdF[(0 + kc) * 512 + l8], d0);
        d1 = mfma_(ad, *(const short8*)&WdF[(2 + kc) * 512 + l8], d1);
      }
      #pragma unroll
      for (int r = 0; r < 4; r++) {
        DB[(q4 + r) * DBS + c]      = f2bf(fmaxf(d0[r], 0.f));
        DB[(q4 + r) * DBS + 16 + c] = f2bf(fmaxf(d1[r], 0.f));
      }
      // same-wave write->read: compiler inserts lgkmcnt
      const short8 ap  = *(const short8*)&DB[c * DBS + q8];
      const short8 wfv = *(const short8*)&WfF[l8];
      f32x4 accp = (f32x4){bfr, bfr, bfr, bfr};
      accp = mfma_(ap, wfv, accp);
      if (c < 2) {
        u16* slot = &XCH[(t >> 3) & 1][0];
        #pragma unroll
        for (int r = 0; r < 4; r++) {
          const int b = q4 + r;
          out[(bb + b) * 40 + (t - 201) * 2 + c] = accp[r];
          slot[b * XCS + (t & 7) * 40 + 14 + c] = f2bf(accp[r]);  // pred -> x(t)
        }
      }
    }
    __syncthreads();                                  // #2: pred in XCH visible
    if (t <= 219) L1_STEP(t & 1, t & 7, XCH[(t >> 3) & 1]);
    __syncthreads();                                  // end of step
  }
}

extern "C" void kernel_launch(void* const* d_in, const int* in_sizes, int n_in,
                              void* d_out, int out_size, void* d_ws, size_t ws_size,
                              hipStream_t stream) {
  (void)in_sizes; (void)n_in; (void)out_size; (void)d_ws; (void)ws_size;
  spc_lstm<<<dim3(256), dim3(768), 0, stream>>>(
      (const float*)d_in[0],  (const float*)d_in[1],
      (const float*)d_in[2],  (const float*)d_in[3],
      (const float*)d_in[4],  (const float*)d_in[5],
      (const float*)d_in[6],  (const float*)d_in[7],
      (const float*)d_in[8],  (const float*)d_in[9],
      (const float*)d_in[10], (const float*)d_in[11],
      (const float*)d_in[12], (const float*)d_in[13],
      (const float*)d_in[14], (float*)d_out);
}

// Round 12
// 433.246 us; speedup vs baseline: 1.0006x; 1.0006x over previous
//
#include <hip/hip_runtime.h>

typedef unsigned short u16;
typedef unsigned int u32;

using short8  = __attribute__((ext_vector_type(8))) short;
using f32x4   = __attribute__((ext_vector_type(4))) float;
using float4v = __attribute__((ext_vector_type(4))) float;
using uint2v  = __attribute__((ext_vector_type(2))) unsigned int;

#define LOG2E 1.44269504088896340736f

// X1 row (per batch): [h1 0:128 | pad] (u16)
#define X1S 136
// H2 row: [h2 0:64 | pad]
#define H2S 72
#define DBS 40
// XCH row stride: 8 steps * 40 + 8 pad (656 B: 16B-aligned, bank-stride 4)
#define XCS 328

__device__ __forceinline__ u16 f2bf(float f) {
  u32 u = __float_as_uint(f);
  return (u16)((u + 0x7FFFu + ((u >> 16) & 1u)) >> 16);
}
// packed f32x2 -> bf16x2, RNE (same rounding as f2bf), 1 instr
__device__ __forceinline__ u32 pkbf(float a, float b) {
  u32 r;
  asm("v_cvt_pk_bf16_f32 %0, %1, %2" : "=v"(r) : "v"(a), "v"(b));
  return r;
}
__device__ __forceinline__ float sigm(float x) {
  return __builtin_amdgcn_rcpf(1.0f + __builtin_amdgcn_exp2f(-LOG2E * x));
}
__device__ __forceinline__ float tanh_(float x) {
  return 1.0f - 2.0f * __builtin_amdgcn_rcpf(1.0f + __builtin_amdgcn_exp2f(2.0f * LOG2E * x));
}
__device__ __forceinline__ f32x4 mfma_(short8 a, short8 b, f32x4 c) {
  return __builtin_amdgcn_mfma_f32_16x16x32_bf16(a, b, c, 0, 0, 0);
}
__device__ __forceinline__ float cellr(float gi, float gf, float gg, float go, float& cr) {
  const float ig = sigm(gi), fg = sigm(gf), g = tanh_(gg), og = sigm(go);
  const float cn = fg * cr + ig * g;
  cr = cn;
  return og * tanh_(cn);
}

// R18b = R17 + occupancy pin (two redundant knobs, one mechanism).
// R17's wu[24] spilled (VGPR stayed 84, 75 MB scratch WRITE): LDS shrink
// 136->40 KB raised LDS-allowed occupancy to 2 blocks/CU (6 waves/EU);
// __launch_bounds__(768,3) is only a MINIMUM, so the backend budgeted
// 512/6 = 84 VGPRs. Grid = 256 = 1 block/CU, so that occupancy is
// unreachable anyway. Pin 3 waves/EU -> 170-VGPR budget:
//  (a) amdgpu_waves_per_eu(3,3)
//  (b) LDSPAD 44 KB -> ~85 KB total LDS > 80 KB, so HW fits only
//      1 block/CU even if (a) is ignored. Costs nothing (grid already
//      1 block/CU).
//  wu overlay (role-disjoint):
//   L1 waves: wu[ty*4+kc]=Whh1 frags, wu[16+ty]      = Wih1 x-frags
//   L2 waves: wu[ty*4+kc]=Wih2 frags, wu[16+ty*2+kc] = Whh2 frags
__global__
__attribute__((amdgpu_flat_work_group_size(768, 768), amdgpu_waves_per_eu(3, 3)))
void spc_lstm(
    const float* __restrict__ xh,   const float* __restrict__ xfr,
    const float* __restrict__ Wih1, const float* __restrict__ Whh1,
    const float* __restrict__ bih1, const float* __restrict__ bhh1,
    const float* __restrict__ Wih2, const float* __restrict__ Whh2,
    const float* __restrict__ bih2, const float* __restrict__ bhh2,
    const float* __restrict__ Wd,   const float* __restrict__ bd,
    const float* __restrict__ Wf,   const float* __restrict__ bfv,
    const float* __restrict__ ob,   float* __restrict__ out)
{
  __shared__ __align__(16) u16 X1[2][16 * X1S];   //  8704 B
  __shared__ __align__(16) u16 H2B[2][16 * H2S];  //  4608 B
  __shared__ __align__(16) u16 DB[16 * DBS];      //  1280 B
  __shared__ __align__(16) u16 WdF[4 * 512];      //  4096 B
  __shared__ __align__(16) u16 WfF[512];          //  1024 B
  __shared__ __align__(16) u16 XCH[2][16 * XCS];  // 20992 B x chunk ring
  __shared__ __align__(16) u16 LDSPAD[22016];     // 44032 B occupancy pad
  // total ~85 KB -> 1 block/CU by LDS

  const int tid = threadIdx.x;
  const int wv  = tid >> 6;          // 0..11
  const int l   = tid & 63;
  const int c   = l & 15;
  const int q   = l >> 4;
  const int bb  = blockIdx.x << 4;
  const bool isL1 = (wv < 8);
  const bool isL2 = !isL1;
  const int  wv8  = wv - 8;

  // keep LDSPAD alive (never executes: xh is never null)
  if (xh == nullptr) LDSPAD[tid] = (u16)tid;

  // hoisted lane-offsets (u16 indices)
  const int cX1 = c * X1S, cH2 = c * H2S, cXC = c * XCS;
  const int l8 = l * 8, q8 = q * 8, q4 = q * 4;
  const int u2  = wv * 16 + c;       // L1 unit col
  const int u2b = wv8 * 16 + c;      // L2 unit col

  // Role-overlaid persistent weight registers (96 VGPR):
  //  L1: wu[ty*4+kc]=Whh1, wu[16+ty]=Wih1-x (q>=2 lanes zero)
  //  L2: wu[ty*4+kc]=Wih2, wu[16+ty*2+kc]=Whh2
  short8 wu[24];
  float  br[4];
  float  cs0 = 0.f, cs1 = 0.f, cs2 = 0.f, cs3 = 0.f;

  // ---- zero activation + chunk LDS ----
  for (int i = tid; i < 2 * 16 * X1S; i += 768) ((u16*)X1)[i] = 0;
  for (int i = tid; i < 2 * 16 * H2S; i += 768) ((u16*)H2B)[i] = 0;
  for (int i = tid; i < 16 * DBS; i += 768) DB[i] = 0;
  for (int i = tid; i < 2 * 16 * XCS; i += 768) ((u16*)XCH)[i] = 0;
  __syncthreads();

  // ---- decoder-head weight LDS (cold path only) ----
  for (int i = tid; i < 4 * 512; i += 768) {          // Wd tiles (ww, kc2)
    const int tix = i >> 9, e = i & 511, k = e >> 4, n = e & 15;
    const int ww = tix >> 1, kc2 = tix & 1;
    WdF[tix * 512 + ((k >> 3) * 16 + n) * 8 + (k & 7)] =
        f2bf(Wd[(ww * 16 + n) * 64 + kc2 * 32 + k]);
  }
  {                                                   // Wf (zeros n>=2)
    const int k = tid >> 4, n = tid & 15;
    if (tid < 512)
      WfF[((k >> 3) * 16 + n) * 8 + (k & 7)] = (n < 2) ? f2bf(Wf[n * 32 + k]) : (u16)0;
  }

  // ---- chunk 0 load (L2 waves): steps 0-7 into XCH[0] ----
  if (isL2) {
    const int i0 = tid - 512;
    #pragma unroll
    for (int p = 0; p < 2; p++) {
      const int idx = i0 + p * 256;
      const int r = idx >> 5, rem = idx & 31, st = rem >> 2, hf = rem & 3;
      const float4v v = *(const float4v*)&xh[(bb + r) * 3200 + st * 16 + hf * 4];
      *(uint2v*)&XCH[0][r * XCS + st * 40 + hf * 4] =
          (uint2v){pkbf(v[0], v[1]), pkbf(v[2], v[3])};
    }
  }

  // ---- register weights / biases (role-overlaid) ----
  if (isL1) {
    #pragma unroll
    for (int ty = 0; ty < 4; ty++) {
      const int g = ty * 128 + wv * 16 + c;
      br[ty] = bih1[g] + bhh1[g];
      #pragma unroll
      for (int kc = 0; kc < 4; kc++) {
        short8 v;
        #pragma unroll
        for (int j = 0; j < 8; j++)
          v[j] = (short)f2bf(Whh1[g * 128 + kc * 32 + q * 8 + j]);
        wu[ty * 4 + kc] = v;
      }
      short8 vx;                                      // Wih1 x-frag: k = q*8+j
      #pragma unroll
      for (int j = 0; j < 8; j++)
        vx[j] = (q < 2) ? (short)f2bf(Wih1[g * 16 + q * 8 + j]) : (short)0;
      wu[16 + ty] = vx;
    }
  } else {
    #pragma unroll
    for (int ty = 0; ty < 4; ty++) {
      const int g2 = ty * 64 + wv8 * 16 + c;
      br[ty] = bih2[g2] + bhh2[g2];
      #pragma unroll
      for (int kc = 0; kc < 4; kc++) {                // Wih2 frags (k = q*8+j + 32*kc)
        short8 v;
        #pragma unroll
        for (int j = 0; j < 8; j++)
          v[j] = (short)f2bf(Wih2[g2 * 128 + kc * 32 + q * 8 + j]);
        wu[ty * 4 + kc] = v;
      }
      #pragma unroll
      for (int kc = 0; kc < 2; kc++) {                // Whh2 frags
        short8 v;
        #pragma unroll
        for (int j = 0; j < 8; j++)
          v[j] = (short)f2bf(Whh2[g2 * 64 + kc * 32 + q * 8 + j]);
        wu[16 + ty * 2 + kc] = v;
      }
    }
  }
  float bdr0 = 0.f, bdr1 = 0.f, bfr = 0.f;
  if (wv == 8) {
    bdr0 = bd[c];
    bdr1 = bd[16 + c];
    if (c < 2) bfr = bfv[c] + ob[c];
  }
  __syncthreads();

// ---- step macros (PAR/SLOT may be constants (hot) or runtime (decoder)) ----
#define L2_STEP(PAR)                                                          \
  do { if (isL2) {                                                            \
    const u16* Xc_ = X1[(PAR)];                                               \
    const u16* Hp_ = H2B[(PAR)];                                              \
    u16* Hd_ = H2B[(PAR) ^ 1];                                                \
    f32x4 a0 = (f32x4){br[0], br[0], br[0], br[0]};                           \
    f32x4 a1 = (f32x4){br[1], br[1], br[1], br[1]};                           \
    f32x4 a2 = (f32x4){br[2], br[2], br[2], br[2]};                           \
    f32x4 a3 = (f32x4){br[3], br[3], br[3], br[3]};                           \
    __builtin_amdgcn_s_setprio(1);                                            \
    _Pragma("unroll") for (int kc = 0; kc < 4; kc++) {                        \
      const short8 fh = *(const short8*)&Xc_[cX1 + kc * 32 + q8];             \
      a0 = mfma_(fh, wu[0 * 4 + kc], a0);                                     \
      a1 = mfma_(fh, wu[1 * 4 + kc], a1);                                     \
      a2 = mfma_(fh, wu[2 * 4 + kc], a2);                                     \
      a3 = mfma_(fh, wu[3 * 4 + kc], a3);                                     \
    }                                                                         \
    _Pragma("unroll") for (int kc = 0; kc < 2; kc++) {                        \
      const short8 hh = *(const short8*)&Hp_[cH2 + kc * 32 + q8];             \
      a0 = mfma_(hh, wu[16 + 0 * 2 + kc], a0);                                \
      a1 = mfma_(hh, wu[16 + 1 * 2 + kc], a1);                                \
      a2 = mfma_(hh, wu[16 + 2 * 2 + kc], a2);                                \
      a3 = mfma_(hh, wu[16 + 3 * 2 + kc], a3);                                \
    }                                                                         \
    __builtin_amdgcn_s_setprio(0);                                            \
    const float h0_ = cellr(a0[0], a1[0], a2[0], a3[0], cs0);                 \
    const float h1_ = cellr(a0[1], a1[1], a2[1], a3[1], cs1);                 \
    const float h2_ = cellr(a0[2], a1[2], a2[2], a3[2], cs2);                 \
    const float h3_ = cellr(a0[3], a1[3], a2[3], a3[3], cs3);                 \
    const u32 p01 = pkbf(h0_, h1_), p23 = pkbf(h2_, h3_);                     \
    Hd_[(q4 + 0) * H2S + u2b] = (u16)p01;                                     \
    Hd_[(q4 + 1) * H2S + u2b] = (u16)(p01 >> 16);                             \
    Hd_[(q4 + 2) * H2S + u2b] = (u16)p23;                                     \
    Hd_[(q4 + 3) * H2S + u2b] = (u16)(p23 >> 16);                             \
  } } while (0)

#define L1_STEP(PAR, SLOT, XRP)                                               \
  do { if (isL1) {                                                            \
    const u16* Xc_ = X1[(PAR)];                                               \
    u16* Xn_ = X1[(PAR) ^ 1];                                                 \
    f32x4 a0 = (f32x4){br[0], br[0], br[0], br[0]};                           \
    f32x4 a1 = (f32x4){br[1], br[1], br[1], br[1]};                           \
    f32x4 a2 = (f32x4){br[2], br[2], br[2], br[2]};                           \
    f32x4 a3 = (f32x4){br[3], br[3], br[3], br[3]};                           \
    __builtin_amdgcn_s_setprio(1);                                            \
    _Pragma("unroll") for (int kc = 0; kc < 4; kc++) {                        \
      const short8 ah = *(const short8*)&Xc_[cX1 + kc * 32 + q8];             \
      a0 = mfma_(ah, wu[0 * 4 + kc], a0);                                     \
      a1 = mfma_(ah, wu[1 * 4 + kc], a1);                                     \
      a2 = mfma_(ah, wu[2 * 4 + kc], a2);                                     \
      a3 = mfma_(ah, wu[3 * 4 + kc], a3);                                     \
    }                                                                         \
    {                                                                         \
      const short8 ax = *(const short8*)&(XRP)[cXC + (SLOT) * 40 + q8];       \
      a0 = mfma_(ax, wu[16 + 0], a0);                                         \
      a1 = mfma_(ax, wu[16 + 1], a1);                                         \
      a2 = mfma_(ax, wu[16 + 2], a2);                                         \
      a3 = mfma_(ax, wu[16 + 3], a3);                                         \
    }                                                                         \
    __builtin_amdgcn_s_setprio(0);                                            \
    const float h0_ = cellr(a0[0], a1[0], a2[0], a3[0], cs0);                 \
    const float h1_ = cellr(a0[1], a1[1], a2[1], a3[1], cs1);                 \
    const float h2_ = cellr(a0[2], a1[2], a2[2], a3[2], cs2);                 \
    const float h3_ = cellr(a0[3], a1[3], a2[3], a3[3], cs3);                 \
    const u32 p01 = pkbf(h0_, h1_), p23 = pkbf(h2_, h3_);                     \
    Xn_[(q4 + 0) * X1S + u2] = (u16)p01;                                      \
    Xn_[(q4 + 1) * X1S + u2] = (u16)(p01 >> 16);                              \
    Xn_[(q4 + 2) * X1S + u2] = (u16)p23;                                      \
    Xn_[(q4 + 3) * X1S + u2] = (u16)(p23 >> 16);                              \
  } } while (0)

  // ---- encoder: 25 chunks x 8 unrolled steps (t = 8m + j, parity = j&1) ----
  #pragma unroll 1
  for (int m = 0; m < 25; ++m) {
    const u16* xr = XCH[m & 1];
    u16* xw = XCH[(m & 1) ^ 1];

    // j = 0: issue next-chunk loads early (hide HBM under L2 MFMAs)
    float4v stg0, stg1;
    const bool doLd = isL2 && (m < 24);
    const int i0 = tid - 512;
    const int r0 = i0 >> 5, rem0 = i0 & 31, st0 = rem0 >> 2, hf0 = rem0 & 3;
    const int i1 = i0 + 256;
    const int r1 = i1 >> 5, rem1 = i1 & 31, st1 = rem1 >> 2, hf1 = rem1 & 3;
    if (doLd) {
      const int t0 = (m + 1) << 3;
      stg0 = *(const float4v*)&xh[(bb + r0) * 3200 + (t0 + st0) * 16 + hf0 * 4];
      stg1 = *(const float4v*)&xh[(bb + r1) * 3200 + (t0 + st1) * 16 + hf1 * 4];
    }
    if (m) L2_STEP(0);
    if (doLd) {
      *(uint2v*)&xw[r0 * XCS + st0 * 40 + hf0 * 4] =
          (uint2v){pkbf(stg0[0], stg0[1]), pkbf(stg0[2], stg0[3])};
      *(uint2v*)&xw[r1 * XCS + st1 * 40 + hf1 * 4] =
          (uint2v){pkbf(stg1[0], stg1[1]), pkbf(stg1[2], stg1[3])};
    } else if (isL2 && m == 24) {                     // decoder chunk 25 (xfr)
      for (int e = i0; e < 16 * 8 * 14; e += 256) {
        const int r = e / 112, rem2 = e % 112, st = rem2 / 14, f = rem2 % 14;
        xw[r * XCS + st * 40 + f] = f2bf(xfr[(bb + r) * 280 + st * 14 + f]);
      }
      if (i0 < 32) {                                  // s=0 feats 14,15
        const int r = i0 >> 1, f = 14 + (i0 & 1);
        xw[r * XCS + f] = f2bf(xh[(bb + r) * 3200 + 199 * 16 + f]);
      }
    }
    L1_STEP(0, 0, xr);
    __syncthreads();

    L2_STEP(1); L1_STEP(1, 1, xr); __syncthreads();
    L2_STEP(0); L1_STEP(0, 2, xr); __syncthreads();
    L2_STEP(1); L1_STEP(1, 3, xr); __syncthreads();
    L2_STEP(0); L1_STEP(0, 4, xr); __syncthreads();
    L2_STEP(1); L1_STEP(1, 5, xr); __syncthreads();
    L2_STEP(0); L1_STEP(0, 6, xr); __syncthreads();
    L2_STEP(1); L1_STEP(1, 7, xr); __syncthreads();
  }

  // ---- t = 200 (first decoder input, no head yet) + load chunk 26 ----
  {
    L2_STEP(0);
    if (isL2) {                                       // chunk 26 -> XCH[0]
      u16* dst = (u16*)XCH[0];
      const int i0 = tid - 512;
      for (int e = i0; e < 16 * 8 * 14; e += 256) {
        const int r = e / 112, rem2 = e % 112, st = rem2 / 14, f = rem2 % 14;
        dst[r * XCS + st * 40 + f] = f2bf(xfr[(bb + r) * 280 + (8 + st) * 14 + f]);
      }
    }
    L1_STEP(0, 0, XCH[1]);
    __syncthreads();
  }

  // ---- decoder: t = 201..220 (cold path, rolled) ----
  #pragma unroll 1
  for (int t = 201; t <= 220; ++t) {
    L2_STEP(t & 1);
    if (isL2 && t == 208) {                           // chunk 27 -> XCH[1]
      u16* dst = (u16*)XCH[1];
      const int i0 = tid - 512;
      for (int e = i0; e < 16 * 8 * 14; e += 256) {
        const int r = e / 112, rem2 = e % 112, st = rem2 / 14, f = rem2 % 14;
        if (16 + st < 20)
          dst[r * XCS + st * 40 + f] = f2bf(xfr[(bb + r) * 280 + (16 + st) * 14 + f]);
      }
    }
    __syncthreads();                                  // #1: h2(t-1) visible
    if (wv == 8) {
      u16* Hd_ = H2B[(t & 1) ^ 1];
      f32x4 d0 = (f32x4){bdr0, bdr0, bdr0, bdr0};
      f32x4 d1 = (f32x4){bdr1, bdr1, bdr1, bdr1};
      #pragma unroll
      for (int kc = 0; kc < 2; kc++) {
        const short8 ad = *(const short8*)&Hd_[cH2 + kc * 32 + q8];
        d0 = mfma_(ad, *(const short8*)&WdF[(0 + kc) * 512 + l8], d0);
        d1 = mfma_(ad, *(const short8*)&WdF[(2 + kc) * 512 + l8], d1);
      }
      #pragma unroll
      for (int r = 0; r < 4; r++) {
        DB[(q4 + r) * DBS + c]      = f2bf(fmaxf(d0[r], 0.f));
        DB[(q4 + r) * DBS + 16 + c] = f2bf(fmaxf(d1[r], 0.f));
      }
      // same-wave write->read: compiler inserts lgkmcnt
      const short8 ap  = *(const short8*)&DB[c * DBS + q8];
      const short8 wfv = *(const short8*)&WfF[l8];
      f32x4 accp = (f32x4){bfr, bfr, bfr, bfr};
      accp = mfma_(ap, wfv, accp);
      if (c < 2) {
        u16* slot = &XCH[(t >> 3) & 1][0];
        #pragma unroll
        for (int r = 0; r < 4; r++) {
          const int b = q4 + r;
          out[(bb + b) * 40 + (t - 201) * 2 + c] = accp[r];
          slot[b * XCS + (t & 7) * 40 + 14 + c] = f2bf(accp[r]);  // pred -> x(t)
        }
      }
    }
    __syncthreads();                                  // #2: pred in XCH visible
    if (t <= 219) L1_STEP(t & 1, t & 7, XCH[(t >> 3) & 1]);
    __syncthreads();                                  // end of step
  }
}

extern "C" void kernel_launch(void* const* d_in, const int* in_sizes, int n_in,
                              void* d_out, int out_size, void* d_ws, size_t ws_size,
                              hipStream_t stream) {
  (void)in_sizes; (void)n_in; (void)out_size; (void)d_ws; (void)ws_size;
  spc_lstm<<<dim3(256), dim3(768), 0, stream>>>(
      (const float*)d_in[0],  (const float*)d_in[1],
      (const float*)d_in[2],  (const float*)d_in[3],
      (const float*)d_in[4],  (const float*)d_in[5],
      (const float*)d_in[6],  (const float*)d_in[7],
      (const float*)d_in[8],  (const float*)d_in[9],
      (const float*)d_in[10], (const float*)d_in[11],
      (const float*)d_in[12], (const float*)d_in[13],
      (const float*)d_in[14], (float*)d_out);
}

// Round 16
// 416.327 us; speedup vs baseline: 1.0413x; 1.0406x over previous
//
#include <hip/hip_runtime.h>

typedef unsigned short u16;
typedef unsigned int u32;

using short8  = __attribute__((ext_vector_type(8))) short;
using f32x4   = __attribute__((ext_vector_type(4))) float;
using float4v = __attribute__((ext_vector_type(4))) float;
using uint2v  = __attribute__((ext_vector_type(2))) unsigned int;

#define LOG2E 1.44269504088896340736f

// X1 row (per batch): [h1 0:128 | pad] (u16)
#define X1S 136
// H2 row: [h2 0:64 | pad]
#define H2S 72
#define DBS 40
// XCH row stride: 8 steps * 40 + 8 pad (656 B: 16B-aligned, bank-stride 4)
#define XCS 328

__device__ __forceinline__ u16 f2bf(float f) {
  u32 u = __float_as_uint(f);
  return (u16)((u + 0x7FFFu + ((u >> 16) & 1u)) >> 16);
}
// packed f32x2 -> bf16x2, RNE (same rounding as f2bf), 1 instr
__device__ __forceinline__ u32 pkbf(float a, float b) {
  u32 r;
  asm("v_cvt_pk_bf16_f32 %0, %1, %2" : "=v"(r) : "v"(a), "v"(b));
  return r;
}
__device__ __forceinline__ float sigm(float x) {
  return __builtin_amdgcn_rcpf(1.0f + __builtin_amdgcn_exp2f(-LOG2E * x));
}
__device__ __forceinline__ float tanh_(float x) {
  return 1.0f - 2.0f * __builtin_amdgcn_rcpf(1.0f + __builtin_amdgcn_exp2f(2.0f * LOG2E * x));
}
__device__ __forceinline__ f32x4 mfma_(short8 a, short8 b, f32x4 c) {
  return __builtin_amdgcn_mfma_f32_16x16x32_bf16(a, b, c, 0, 0, 0);
}
__device__ __forceinline__ float cellr(float gi, float gf, float gg, float go, float& cr) {
  const float ig = sigm(gi), fg = sigm(gf), g = tanh_(gg), og = sigm(go);
  const float cn = fg * cr + ig * g;
  cr = cn;
  return og * tanh_(cn);
}

// R19 = R16 + PARTIAL weights-to-registers, sized under the empirical cap.
// Evidence: 768-thr builds always report VGPR=84; 64 weight-regs fit (R16,
// WRITE 10MB), 96 spilled (R17, WRITE 75MB); occupancy attributes + LDS pad
// changed nothing (R18b bit-identical to R17; pad was DCE'd). So probe 80:
//  - L1 waves: wu[0..15]=Whh1 (64) + wu[16..19]=Wih1x (16) -> 80 regs,
//    W1xF LDS array deleted (-32 reads/step)
//  - L2 waves: wu[0..7]=Whh2 (32) + wu[8..15]=Wih2 kc0,1 (32) -> 64 regs
//    (fills slots R16 left unused; no added pressure), W2F halved to kc2,3
//    (-32 reads/step)
// Per-step LDS reads 160 -> 96 b128 (~-40% on the dominant pipe).
// MFMA kc order preserved (0,1 regs then 2,3 LDS) -> numerics identical.
__global__ __launch_bounds__(768, 3) void spc_lstm(
    const float* __restrict__ xh,   const float* __restrict__ xfr,
    const float* __restrict__ Wih1, const float* __restrict__ Whh1,
    const float* __restrict__ bih1, const float* __restrict__ bhh1,
    const float* __restrict__ Wih2, const float* __restrict__ Whh2,
    const float* __restrict__ bih2, const float* __restrict__ bhh2,
    const float* __restrict__ Wd,   const float* __restrict__ bd,
    const float* __restrict__ Wf,   const float* __restrict__ bfv,
    const float* __restrict__ ob,   float* __restrict__ out)
{
  __shared__ __align__(16) u16 X1[2][16 * X1S];   //  8704 B
  __shared__ __align__(16) u16 H2B[2][16 * H2S];  //  4608 B
  __shared__ __align__(16) u16 DB[16 * DBS];      //  1280 B
  __shared__ __align__(16) u16 W2F[32 * 512];     // 32768 B (Wih2 kc=2,3 only)
  __shared__ __align__(16) u16 WdF[4 * 512];      //  4096 B
  __shared__ __align__(16) u16 WfF[512];          //  1024 B
  __shared__ __align__(16) u16 XCH[2][16 * XCS];  // 20992 B x chunk ring
  // total ~73.5 KB

  const int tid = threadIdx.x;
  const int wv  = tid >> 6;          // 0..11
  const int l   = tid & 63;
  const int c   = l & 15;
  const int q   = l >> 4;
  const int bb  = blockIdx.x << 4;
  const bool isL1 = (wv < 8);
  const bool isL2 = !isL1;
  const int  wv8  = wv - 8;

  // hoisted lane-offsets (u16 indices)
  const int cX1 = c * X1S, cH2 = c * H2S, cXC = c * XCS;
  const int l8 = l * 8, q8 = q * 8, q4 = q * 4;
  const int u2  = wv * 16 + c;       // L1 unit col
  const int u2b = wv8 * 16 + c;      // L2 unit col
  const int w2o = wv8 * 8;           // W2F tile base (halved layout)

  // Role-overlaid persistent weight registers (80 VGPR):
  //  L1: wu[ty*4+kc]=Whh1, wu[16+ty]=Wih1-x (q>=2 lanes zero)
  //  L2: wu[ty*2+kc]=Whh2 (0..7), wu[8+ty*2+kc]=Wih2 kc0,1 (8..15)
  short8 wu[20];
  float  br[4];
  float  cs0 = 0.f, cs1 = 0.f, cs2 = 0.f, cs3 = 0.f;

  // ---- zero activation + chunk LDS ----
  for (int i = tid; i < 2 * 16 * X1S; i += 768) ((u16*)X1)[i] = 0;
  for (int i = tid; i < 2 * 16 * H2S; i += 768) ((u16*)H2B)[i] = 0;
  for (int i = tid; i < 16 * DBS; i += 768) DB[i] = 0;
  for (int i = tid; i < 2 * 16 * XCS; i += 768) ((u16*)XCH)[i] = 0;
  __syncthreads();

  // ---- weight LDS fills (fragment-linear: (k,n) -> ((k>>3)*16+n)*8 + (k&7)) ----
  for (int i = tid; i < 32 * 512; i += 768) {         // Wih2 kc=2,3 tiles
    const int rid = i >> 9, e = i & 511, k = e >> 4, n = e & 15;
    const int ww = rid >> 3, ty = (rid >> 1) & 3, kch = rid & 1;
    const int g = ty * 64 + ww * 16 + n;
    W2F[rid * 512 + ((k >> 3) * 16 + n) * 8 + (k & 7)] =
        f2bf(Wih2[g * 128 + (2 + kch) * 32 + k]);
  }
  for (int i = tid; i < 4 * 512; i += 768) {          // Wd tiles (ww, kc2)
    const int tix = i >> 9, e = i & 511, k = e >> 4, n = e & 15;
    const int ww = tix >> 1, kc2 = tix & 1;
    WdF[tix * 512 + ((k >> 3) * 16 + n) * 8 + (k & 7)] =
        f2bf(Wd[(ww * 16 + n) * 64 + kc2 * 32 + k]);
  }
  {                                                   // Wf (zeros n>=2)
    const int k = tid >> 4, n = tid & 15;
    if (tid < 512)
      WfF[((k >> 3) * 16 + n) * 8 + (k & 7)] = (n < 2) ? f2bf(Wf[n * 32 + k]) : (u16)0;
  }

  // ---- chunk 0 load (L2 waves): steps 0-7 into XCH[0] ----
  if (isL2) {
    const int i0 = tid - 512;
    #pragma unroll
    for (int p = 0; p < 2; p++) {
      const int idx = i0 + p * 256;
      const int r = idx >> 5, rem = idx & 31, st = rem >> 2, hf = rem & 3;
      const float4v v = *(const float4v*)&xh[(bb + r) * 3200 + st * 16 + hf * 4];
      *(uint2v*)&XCH[0][r * XCS + st * 40 + hf * 4] =
          (uint2v){pkbf(v[0], v[1]), pkbf(v[2], v[3])};
    }
  }

  // ---- register weights / biases (role-overlaid) ----
  if (isL1) {
    #pragma unroll
    for (int ty = 0; ty < 4; ty++) {
      const int g = ty * 128 + wv * 16 + c;
      br[ty] = bih1[g] + bhh1[g];
      #pragma unroll
      for (int kc = 0; kc < 4; kc++) {
        short8 v;
        #pragma unroll
        for (int j = 0; j < 8; j++)
          v[j] = (short)f2bf(Whh1[g * 128 + kc * 32 + q * 8 + j]);
        wu[ty * 4 + kc] = v;
      }
      short8 vx;                                      // Wih1 x-frag: k = q*8+j
      #pragma unroll
      for (int j = 0; j < 8; j++)
        vx[j] = (q < 2) ? (short)f2bf(Wih1[g * 16 + q * 8 + j]) : (short)0;
      wu[16 + ty] = vx;
    }
  } else {
    #pragma unroll
    for (int ty = 0; ty < 4; ty++) {
      const int g2 = ty * 64 + wv8 * 16 + c;
      br[ty] = bih2[g2] + bhh2[g2];
      #pragma unroll
      for (int kc = 0; kc < 2; kc++) {                // Whh2 frags -> wu[0..7]
        short8 v;
        #pragma unroll
        for (int j = 0; j < 8; j++)
          v[j] = (short)f2bf(Whh2[g2 * 64 + kc * 32 + q * 8 + j]);
        wu[ty * 2 + kc] = v;
      }
      #pragma unroll
      for (int kc = 0; kc < 2; kc++) {                // Wih2 kc0,1 -> wu[8..15]
        short8 v;
        #pragma unroll
        for (int j = 0; j < 8; j++)
          v[j] = (short)f2bf(Wih2[g2 * 128 + kc * 32 + q * 8 + j]);
        wu[8 + ty * 2 + kc] = v;
      }
    }
  }
  float bdr0 = 0.f, bdr1 = 0.f, bfr = 0.f;
  if (wv == 8) {
    bdr0 = bd[c];
    bdr1 = bd[16 + c];
    if (c < 2) bfr = bfv[c] + ob[c];
  }
  __syncthreads();

// ---- step macros (PAR/SLOT may be constants (hot) or runtime (decoder)) ----
#define L2_STEP(PAR)                                                          \
  do { if (isL2) {                                                            \
    const u16* Xc_ = X1[(PAR)];                                               \
    const u16* Hp_ = H2B[(PAR)];                                              \
    u16* Hd_ = H2B[(PAR) ^ 1];                                                \
    f32x4 a0 = (f32x4){br[0], br[0], br[0], br[0]};                           \
    f32x4 a1 = (f32x4){br[1], br[1], br[1], br[1]};                           \
    f32x4 a2 = (f32x4){br[2], br[2], br[2], br[2]};                           \
    f32x4 a3 = (f32x4){br[3], br[3], br[3], br[3]};                           \
    __builtin_amdgcn_s_setprio(1);                                            \
    _Pragma("unroll") for (int kc = 0; kc < 2; kc++) {                        \
      const short8 fh = *(const short8*)&Xc_[cX1 + kc * 32 + q8];             \
      a0 = mfma_(fh, wu[8 + 0 * 2 + kc], a0);                                 \
      a1 = mfma_(fh, wu[8 + 1 * 2 + kc], a1);                                 \
      a2 = mfma_(fh, wu[8 + 2 * 2 + kc], a2);                                 \
      a3 = mfma_(fh, wu[8 + 3 * 2 + kc], a3);                                 \
    }                                                                         \
    _Pragma("unroll") for (int kc = 2; kc < 4; kc++) {                        \
      const short8 fh = *(const short8*)&Xc_[cX1 + kc * 32 + q8];             \
      const int kh = kc - 2;                                                  \
      a0 = mfma_(fh, *(const short8*)&W2F[(w2o + 0 * 2 + kh) * 512 + l8], a0);\
      a1 = mfma_(fh, *(const short8*)&W2F[(w2o + 1 * 2 + kh) * 512 + l8], a1);\
      a2 = mfma_(fh, *(const short8*)&W2F[(w2o + 2 * 2 + kh) * 512 + l8], a2);\
      a3 = mfma_(fh, *(const short8*)&W2F[(w2o + 3 * 2 + kh) * 512 + l8], a3);\
    }                                                                         \
    _Pragma("unroll") for (int kc = 0; kc < 2; kc++) {                        \
      const short8 hh = *(const short8*)&Hp_[cH2 + kc * 32 + q8];             \
      a0 = mfma_(hh, wu[0 * 2 + kc], a0);                                     \
      a1 = mfma_(hh, wu[1 * 2 + kc], a1);                                     \
      a2 = mfma_(hh, wu[2 * 2 + kc], a2);                                     \
      a3 = mfma_(hh, wu[3 * 2 + kc], a3);                                     \
    }                                                                         \
    __builtin_amdgcn_s_setprio(0);                                            \
    const float h0_ = cellr(a0[0], a1[0], a2[0], a3[0], cs0);                 \
    const float h1_ = cellr(a0[1], a1[1], a2[1], a3[1], cs1);                 \
    const float h2_ = cellr(a0[2], a1[2], a2[2], a3[2], cs2);                 \
    const float h3_ = cellr(a0[3], a1[3], a2[3], a3[3], cs3);                 \
    const u32 p01 = pkbf(h0_, h1_), p23 = pkbf(h2_, h3_);                     \
    Hd_[(q4 + 0) * H2S + u2b] = (u16)p01;                                     \
    Hd_[(q4 + 1) * H2S + u2b] = (u16)(p01 >> 16);                             \
    Hd_[(q4 + 2) * H2S + u2b] = (u16)p23;                                     \
    Hd_[(q4 + 3) * H2S + u2b] = (u16)(p23 >> 16);                             \
  } } while (0)

#define L1_STEP(PAR, SLOT, XRP)                                               \
  do { if (isL1) {                                                            \
    const u16* Xc_ = X1[(PAR)];                                               \
    u16* Xn_ = X1[(PAR) ^ 1];                                                 \
    f32x4 a0 = (f32x4){br[0], br[0], br[0], br[0]};                           \
    f32x4 a1 = (f32x4){br[1], br[1], br[1], br[1]};                           \
    f32x4 a2 = (f32x4){br[2], br[2], br[2], br[2]};                           \
    f32x4 a3 = (f32x4){br[3], br[3], br[3], br[3]};                           \
    __builtin_amdgcn_s_setprio(1);                                            \
    _Pragma("unroll") for (int kc = 0; kc < 4; kc++) {                        \
      const short8 ah = *(const short8*)&Xc_[cX1 + kc * 32 + q8];             \
      a0 = mfma_(ah, wu[0 * 4 + kc], a0);                                     \
      a1 = mfma_(ah, wu[1 * 4 + kc], a1);                                     \
      a2 = mfma_(ah, wu[2 * 4 + kc], a2);                                     \
      a3 = mfma_(ah, wu[3 * 4 + kc], a3);                                     \
    }                                                                         \
    {                                                                         \
      const short8 ax = *(const short8*)&(XRP)[cXC + (SLOT) * 40 + q8];       \
      a0 = mfma_(ax, wu[16 + 0], a0);                                         \
      a1 = mfma_(ax, wu[16 + 1], a1);                                         \
      a2 = mfma_(ax, wu[16 + 2], a2);                                         \
      a3 = mfma_(ax, wu[16 + 3], a3);                                         \
    }                                                                         \
    __builtin_amdgcn_s_setprio(0);                                            \
    const float h0_ = cellr(a0[0], a1[0], a2[0], a3[0], cs0);                 \
    const float h1_ = cellr(a0[1], a1[1], a2[1], a3[1], cs1);                 \
    const float h2_ = cellr(a0[2], a1[2], a2[2], a3[2], cs2);                 \
    const float h3_ = cellr(a0[3], a1[3], a2[3], a3[3], cs3);                 \
    const u32 p01 = pkbf(h0_, h1_), p23 = pkbf(h2_, h3_);                     \
    Xn_[(q4 + 0) * X1S + u2] = (u16)p01;                                      \
    Xn_[(q4 + 1) * X1S + u2] = (u16)(p01 >> 16);                              \
    Xn_[(q4 + 2) * X1S + u2] = (u16)p23;                                      \
    Xn_[(q4 + 3) * X1S + u2] = (u16)(p23 >> 16);                              \
  } } while (0)

  // ---- encoder: 25 chunks x 8 unrolled steps (t = 8m + j, parity = j&1) ----
  #pragma unroll 1
  for (int m = 0; m < 25; ++m) {
    const u16* xr = XCH[m & 1];
    u16* xw = XCH[(m & 1) ^ 1];

    // j = 0: issue next-chunk loads early (hide HBM under L2 MFMAs)
    float4v stg0, stg1;
    const bool doLd = isL2 && (m < 24);
    const int i0 = tid - 512;
    const int r0 = i0 >> 5, rem0 = i0 & 31, st0 = rem0 >> 2, hf0 = rem0 & 3;
    const int i1 = i0 + 256;
    const int r1 = i1 >> 5, rem1 = i1 & 31, st1 = rem1 >> 2, hf1 = rem1 & 3;
    if (doLd) {
      const int t0 = (m + 1) << 3;
      stg0 = *(const float4v*)&xh[(bb + r0) * 3200 + (t0 + st0) * 16 + hf0 * 4];
      stg1 = *(const float4v*)&xh[(bb + r1) * 3200 + (t0 + st1) * 16 + hf1 * 4];
    }
    if (m) L2_STEP(0);
    if (doLd) {
      *(uint2v*)&xw[r0 * XCS + st0 * 40 + hf0 * 4] =
          (uint2v){pkbf(stg0[0], stg0[1]), pkbf(stg0[2], stg0[3])};
      *(uint2v*)&xw[r1 * XCS + st1 * 40 + hf1 * 4] =
          (uint2v){pkbf(stg1[0], stg1[1]), pkbf(stg1[2], stg1[3])};
    } else if (isL2 && m == 24) {                     // decoder chunk 25 (xfr)
      for (int e = i0; e < 16 * 8 * 14; e += 256) {
        const int r = e / 112, rem2 = e % 112, st = rem2 / 14, f = rem2 % 14;
        xw[r * XCS + st * 40 + f] = f2bf(xfr[(bb + r) * 280 + st * 14 + f]);
      }
      if (i0 < 32) {                                  // s=0 feats 14,15
        const int r = i0 >> 1, f = 14 + (i0 & 1);
        xw[r * XCS + f] = f2bf(xh[(bb + r) * 3200 + 199 * 16 + f]);
      }
    }
    L1_STEP(0, 0, xr);
    __syncthreads();

    L2_STEP(1); L1_STEP(1, 1, xr); __syncthreads();
    L2_STEP(0); L1_STEP(0, 2, xr); __syncthreads();
    L2_STEP(1); L1_STEP(1, 3, xr); __syncthreads();
    L2_STEP(0); L1_STEP(0, 4, xr); __syncthreads();
    L2_STEP(1); L1_STEP(1, 5, xr); __syncthreads();
    L2_STEP(0); L1_STEP(0, 6, xr); __syncthreads();
    L2_STEP(1); L1_STEP(1, 7, xr); __syncthreads();
  }

  // ---- t = 200 (first decoder input, no head yet) + load chunk 26 ----
  {
    L2_STEP(0);
    if (isL2) {                                       // chunk 26 -> XCH[0]
      u16* dst = (u16*)XCH[0];
      const int i0 = tid - 512;
      for (int e = i0; e < 16 * 8 * 14; e += 256) {
        const int r = e / 112, rem2 = e % 112, st = rem2 / 14, f = rem2 % 14;
        dst[r * XCS + st * 40 + f] = f2bf(xfr[(bb + r) * 280 + (8 + st) * 14 + f]);
      }
    }
    L1_STEP(0, 0, XCH[1]);
    __syncthreads();
  }

  // ---- decoder: t = 201..220 (cold path, rolled) ----
  #pragma unroll 1
  for (int t = 201; t <= 220; ++t) {
    L2_STEP(t & 1);
    if (isL2 && t == 208) {                           // chunk 27 -> XCH[1]
      u16* dst = (u16*)XCH[1];
      const int i0 = tid - 512;
      for (int e = i0; e < 16 * 8 * 14; e += 256) {
        const int r = e / 112, rem2 = e % 112, st = rem2 / 14, f = rem2 % 14;
        if (16 + st < 20)
          dst[r * XCS + st * 40 + f] = f2bf(xfr[(bb + r) * 280 + (16 + st) * 14 + f]);
      }
    }
    __syncthreads();                                  // #1: h2(t-1) visible
    if (wv == 8) {
      u16* Hd_ = H2B[(t & 1) ^ 1];
      f32x4 d0 = (f32x4){bdr0, bdr0, bdr0, bdr0};
      f32x4 d1 = (f32x4){bdr1, bdr1, bdr1, bdr1};
      #pragma unroll
      for (int kc = 0; kc < 2; kc++) {
        const short8 ad = *(const short8*)&Hd_[cH2 + kc * 32 + q8];
        d0 = mfma_(ad, *(const short8*)&WdF[(0 + kc) * 512 + l8], d0);
        d1 = mfma_(ad, *(const short8*)&WdF[(2 + kc) * 512 + l8], d1);
      }
      #pragma unroll
      for (int r = 0; r < 4; r++) {
        DB[(q4 + r) * DBS + c]      = f2bf(fmaxf(d0[r], 0.f));
        DB[(q4 + r) * DBS + 16 + c] = f2bf(fmaxf(d1[r], 0.f));
      }
      // same-wave write->read: compiler inserts lgkmcnt
      const short8 ap  = *(const short8*)&DB[c * DBS + q8];
      const short8 wfv = *(const short8*)&WfF[l8];
      f32x4 accp = (f32x4){bfr, bfr, bfr, bfr};
      accp = mfma_(ap, wfv, accp);
      if (c < 2) {
        u16* slot = &XCH[(t >> 3) & 1][0];
        #pragma unroll
        for (int r = 0; r < 4; r++) {
          const int b = q4 + r;
          out[(bb + b) * 40 + (t - 201) * 2 + c] = accp[r];
          slot[b * XCS + (t & 7) * 40 + 14 + c] = f2bf(accp[r]);  // pred -> x(t)
        }
      }
    }
    __syncthreads();                                  // #2: pred in XCH visible
    if (t <= 219) L1_STEP(t & 1, t & 7, XCH[(t >> 3) & 1]);
    __syncthreads();                                  // end of step
  }
}

extern "C" void kernel_launch(void* const* d_in, const int* in_sizes, int n_in,
                              void* d_out, int out_size, void* d_ws, size_t ws_size,
                              hipStream_t stream) {
  (void)in_sizes; (void)n_in; (void)out_size; (void)d_ws; (void)ws_size;
  spc_lstm<<<dim3(256), dim3(768), 0, stream>>>(
      (const float*)d_in[0],  (const float*)d_in[1],
      (const float*)d_in[2],  (const float*)d_in[3],
      (const float*)d_in[4],  (const float*)d_in[5],
      (const float*)d_in[6],  (const float*)d_in[7],
      (const float*)d_in[8],  (const float*)d_in[9],
      (const float*)d_in[10], (const float*)d_in[11],
      (const float*)d_in[12], (const float*)d_in[13],
      (const float*)d_in[14], (float*)d_out);
}

// Round 17
// 406.892 us; speedup vs baseline: 1.0654x; 1.0232x over previous
//
#include <hip/hip_runtime.h>

typedef unsigned short u16;
typedef unsigned int u32;

using short8  = __attribute__((ext_vector_type(8))) short;
using f32x4   = __attribute__((ext_vector_type(4))) float;
using float4v = __attribute__((ext_vector_type(4))) float;
using uint2v  = __attribute__((ext_vector_type(2))) unsigned int;

#define LOG2E 1.44269504088896340736f

// X1 row (per batch): [h1 0:128 | pad] (u16)
#define X1S 136
// H2 row: [h2 0:64 | pad]
#define H2S 72
#define DBS 40
// XCH row stride: 8 steps * 40 + 8 pad (656 B: 16B-aligned, bank-stride 4)
#define XCS 328

__device__ __forceinline__ u16 f2bf(float f) {
  u32 u = __float_as_uint(f);
  return (u16)((u + 0x7FFFu + ((u >> 16) & 1u)) >> 16);
}
// packed f32x2 -> bf16x2, RNE (same rounding as f2bf), 1 instr
__device__ __forceinline__ u32 pkbf(float a, float b) {
  u32 r;
  asm("v_cvt_pk_bf16_f32 %0, %1, %2" : "=v"(r) : "v"(a), "v"(b));
  return r;
}
__device__ __forceinline__ float sigm(float x) {
  return __builtin_amdgcn_rcpf(1.0f + __builtin_amdgcn_exp2f(-LOG2E * x));
}
__device__ __forceinline__ float tanh_(float x) {
  return 1.0f - 2.0f * __builtin_amdgcn_rcpf(1.0f + __builtin_amdgcn_exp2f(2.0f * LOG2E * x));
}
__device__ __forceinline__ f32x4 mfma_(short8 a, short8 b, f32x4 c) {
  return __builtin_amdgcn_mfma_f32_16x16x32_bf16(a, b, c, 0, 0, 0);
}
__device__ __forceinline__ float cellr(float gi, float gf, float gg, float go, float& cr) {
  const float ig = sigm(gi), fg = sigm(gf), g = tanh_(gg), og = sigm(go);
  const float cn = fg * cr + ig * g;
  cr = cn;
  return og * tanh_(cn);
}

// R20 = R19 minus the spilling half. Evidence closes the VGPR model:
// backend pins 84 VGPR on all 768-thr builds; R16's 16-short8 overlay
// (64 weight + 16 acc + ~4 misc = 84) fits EXACTLY; R19's +4 short8
// (Wih1x) spilled (+12.5MB scratch WRITE, +8MB reload FETCH) yet still
// won 13us -> the L2-side change (halved W2F into R16's 8 UNUSED overlay
// slots, zero added pressure) was the pure win.
//  - wu[16] exactly: L1 wu[ty*4+kc]=Whh1; L2 wu[ty*2+kc]=Whh2 (0..7),
//    wu[8+ty*2+kc]=Wih2 kc0,1 (8..15)
//  - L1 x-path reads W1xF from LDS (restored, no spill)
//  - L2 keeps halved W2F (kc2,3 only): per-step LDS reads 160 -> 128
__global__ __launch_bounds__(768, 3) void spc_lstm(
    const float* __restrict__ xh,   const float* __restrict__ xfr,
    const float* __restrict__ Wih1, const float* __restrict__ Whh1,
    const float* __restrict__ bih1, const float* __restrict__ bhh1,
    const float* __restrict__ Wih2, const float* __restrict__ Whh2,
    const float* __restrict__ bih2, const float* __restrict__ bhh2,
    const float* __restrict__ Wd,   const float* __restrict__ bd,
    const float* __restrict__ Wf,   const float* __restrict__ bfv,
    const float* __restrict__ ob,   float* __restrict__ out)
{
  __shared__ __align__(16) u16 X1[2][16 * X1S];   //  8704 B
  __shared__ __align__(16) u16 H2B[2][16 * H2S];  //  4608 B
  __shared__ __align__(16) u16 DB[16 * DBS];      //  1280 B
  __shared__ __align__(16) u16 W1xF[32 * 512];    // 32768 B (zeros k>=16 baked)
  __shared__ __align__(16) u16 W2F[32 * 512];     // 32768 B (Wih2 kc=2,3 only)
  __shared__ __align__(16) u16 WdF[4 * 512];      //  4096 B
  __shared__ __align__(16) u16 WfF[512];          //  1024 B
  __shared__ __align__(16) u16 XCH[2][16 * XCS];  // 20992 B x chunk ring
  // total ~106 KB

  const int tid = threadIdx.x;
  const int wv  = tid >> 6;          // 0..11
  const int l   = tid & 63;
  const int c   = l & 15;
  const int q   = l >> 4;
  const int bb  = blockIdx.x << 4;
  const bool isL1 = (wv < 8);
  const bool isL2 = !isL1;
  const int  wv8  = wv - 8;

  // hoisted lane-offsets (u16 indices)
  const int cX1 = c * X1S, cH2 = c * H2S, cXC = c * XCS;
  const int l8 = l * 8, q8 = q * 8, q4 = q * 4;
  const int u2  = wv * 16 + c;       // L1 unit col
  const int u2b = wv8 * 16 + c;      // L2 unit col
  const int w2o = wv8 * 8;           // W2F tile base (halved layout)

  // Role-overlaid persistent weight registers (64 VGPR, fits at cap 84):
  //  L1: wu[ty*4+kc]=Whh1
  //  L2: wu[ty*2+kc]=Whh2 (0..7), wu[8+ty*2+kc]=Wih2 kc0,1 (8..15)
  short8 wu[16];
  float  br[4];
  float  cs0 = 0.f, cs1 = 0.f, cs2 = 0.f, cs3 = 0.f;

  // ---- zero activation + chunk LDS ----
  for (int i = tid; i < 2 * 16 * X1S; i += 768) ((u16*)X1)[i] = 0;
  for (int i = tid; i < 2 * 16 * H2S; i += 768) ((u16*)H2B)[i] = 0;
  for (int i = tid; i < 16 * DBS; i += 768) DB[i] = 0;
  for (int i = tid; i < 2 * 16 * XCS; i += 768) ((u16*)XCH)[i] = 0;
  __syncthreads();

  // ---- weight LDS fills (fragment-linear: (k,n) -> ((k>>3)*16+n)*8 + (k&7)) ----
  for (int i = tid; i < 32 * 512; i += 768) {         // Wih1 x-frags FULL (zeros k>=16)
    const int T = i >> 9, e = i & 511, k = e >> 4, n = e & 15;
    const int ty = T >> 3, uv = T & 7;
    const int g = ty * 128 + uv * 16 + n;
    W1xF[T * 512 + ((k >> 3) * 16 + n) * 8 + (k & 7)] =
        (k < 16) ? f2bf(Wih1[g * 16 + k]) : (u16)0;
  }
  for (int i = tid; i < 32 * 512; i += 768) {         // Wih2 kc=2,3 tiles
    const int rid = i >> 9, e = i & 511, k = e >> 4, n = e & 15;
    const int ww = rid >> 3, ty = (rid >> 1) & 3, kch = rid & 1;
    const int g = ty * 64 + ww * 16 + n;
    W2F[rid * 512 + ((k >> 3) * 16 + n) * 8 + (k & 7)] =
        f2bf(Wih2[g * 128 + (2 + kch) * 32 + k]);
  }
  for (int i = tid; i < 4 * 512; i += 768) {          // Wd tiles (ww, kc2)
    const int tix = i >> 9, e = i & 511, k = e >> 4, n = e & 15;
    const int ww = tix >> 1, kc2 = tix & 1;
    WdF[tix * 512 + ((k >> 3) * 16 + n) * 8 + (k & 7)] =
        f2bf(Wd[(ww * 16 + n) * 64 + kc2 * 32 + k]);
  }
  {                                                   // Wf (zeros n>=2)
    const int k = tid >> 4, n = tid & 15;
    if (tid < 512)
      WfF[((k >> 3) * 16 + n) * 8 + (k & 7)] = (n < 2) ? f2bf(Wf[n * 32 + k]) : (u16)0;
  }

  // ---- chunk 0 load (L2 waves): steps 0-7 into XCH[0] ----
  if (isL2) {
    const int i0 = tid - 512;
    #pragma unroll
    for (int p = 0; p < 2; p++) {
      const int idx = i0 + p * 256;
      const int r = idx >> 5, rem = idx & 31, st = rem >> 2, hf = rem & 3;
      const float4v v = *(const float4v*)&xh[(bb + r) * 3200 + st * 16 + hf * 4];
      *(uint2v*)&XCH[0][r * XCS + st * 40 + hf * 4] =
          (uint2v){pkbf(v[0], v[1]), pkbf(v[2], v[3])};
    }
  }

  // ---- register weights / biases (role-overlaid) ----
  if (isL1) {
    #pragma unroll
    for (int ty = 0; ty < 4; ty++) {
      const int g = ty * 128 + wv * 16 + c;
      br[ty] = bih1[g] + bhh1[g];
      #pragma unroll
      for (int kc = 0; kc < 4; kc++) {
        short8 v;
        #pragma unroll
        for (int j = 0; j < 8; j++)
          v[j] = (short)f2bf(Whh1[g * 128 + kc * 32 + q * 8 + j]);
        wu[ty * 4 + kc] = v;
      }
    }
  } else {
    #pragma unroll
    for (int ty = 0; ty < 4; ty++) {
      const int g2 = ty * 64 + wv8 * 16 + c;
      br[ty] = bih2[g2] + bhh2[g2];
      #pragma unroll
      for (int kc = 0; kc < 2; kc++) {                // Whh2 frags -> wu[0..7]
        short8 v;
        #pragma unroll
        for (int j = 0; j < 8; j++)
          v[j] = (short)f2bf(Whh2[g2 * 64 + kc * 32 + q * 8 + j]);
        wu[ty * 2 + kc] = v;
      }
      #pragma unroll
      for (int kc = 0; kc < 2; kc++) {                // Wih2 kc0,1 -> wu[8..15]
        short8 v;
        #pragma unroll
        for (int j = 0; j < 8; j++)
          v[j] = (short)f2bf(Wih2[g2 * 128 + kc * 32 + q * 8 + j]);
        wu[8 + ty * 2 + kc] = v;
      }
    }
  }
  float bdr0 = 0.f, bdr1 = 0.f, bfr = 0.f;
  if (wv == 8) {
    bdr0 = bd[c];
    bdr1 = bd[16 + c];
    if (c < 2) bfr = bfv[c] + ob[c];
  }
  __syncthreads();

// ---- step macros (PAR/SLOT may be constants (hot) or runtime (decoder)) ----
#define L2_STEP(PAR)                                                          \
  do { if (isL2) {                                                            \
    const u16* Xc_ = X1[(PAR)];                                               \
    const u16* Hp_ = H2B[(PAR)];                                              \
    u16* Hd_ = H2B[(PAR) ^ 1];                                                \
    f32x4 a0 = (f32x4){br[0], br[0], br[0], br[0]};                           \
    f32x4 a1 = (f32x4){br[1], br[1], br[1], br[1]};                           \
    f32x4 a2 = (f32x4){br[2], br[2], br[2], br[2]};                           \
    f32x4 a3 = (f32x4){br[3], br[3], br[3], br[3]};                           \
    __builtin_amdgcn_s_setprio(1);                                            \
    _Pragma("unroll") for (int kc = 0; kc < 2; kc++) {                        \
      const short8 fh = *(const short8*)&Xc_[cX1 + kc * 32 + q8];             \
      a0 = mfma_(fh, wu[8 + 0 * 2 + kc], a0);                                 \
      a1 = mfma_(fh, wu[8 + 1 * 2 + kc], a1);                                 \
      a2 = mfma_(fh, wu[8 + 2 * 2 + kc], a2);                                 \
      a3 = mfma_(fh, wu[8 + 3 * 2 + kc], a3);                                 \
    }                                                                         \
    _Pragma("unroll") for (int kc = 2; kc < 4; kc++) {                        \
      const short8 fh = *(const short8*)&Xc_[cX1 + kc * 32 + q8];             \
      const int kh = kc - 2;                                                  \
      a0 = mfma_(fh, *(const short8*)&W2F[(w2o + 0 * 2 + kh) * 512 + l8], a0);\
      a1 = mfma_(fh, *(const short8*)&W2F[(w2o + 1 * 2 + kh) * 512 + l8], a1);\
      a2 = mfma_(fh, *(const short8*)&W2F[(w2o + 2 * 2 + kh) * 512 + l8], a2);\
      a3 = mfma_(fh, *(const short8*)&W2F[(w2o + 3 * 2 + kh) * 512 + l8], a3);\
    }                                                                         \
    _Pragma("unroll") for (int kc = 0; kc < 2; kc++) {                        \
      const short8 hh = *(const short8*)&Hp_[cH2 + kc * 32 + q8];             \
      a0 = mfma_(hh, wu[0 * 2 + kc], a0);                                     \
      a1 = mfma_(hh, wu[1 * 2 + kc], a1);                                     \
      a2 = mfma_(hh, wu[2 * 2 + kc], a2);                                     \
      a3 = mfma_(hh, wu[3 * 2 + kc], a3);                                     \
    }                                                                         \
    __builtin_amdgcn_s_setprio(0);                                            \
    const float h0_ = cellr(a0[0], a1[0], a2[0], a3[0], cs0);                 \
    const float h1_ = cellr(a0[1], a1[1], a2[1], a3[1], cs1);                 \
    const float h2_ = cellr(a0[2], a1[2], a2[2], a3[2], cs2);                 \
    const float h3_ = cellr(a0[3], a1[3], a2[3], a3[3], cs3);                 \
    const u32 p01 = pkbf(h0_, h1_), p23 = pkbf(h2_, h3_);                     \
    Hd_[(q4 + 0) * H2S + u2b] = (u16)p01;                                     \
    Hd_[(q4 + 1) * H2S + u2b] = (u16)(p01 >> 16);                             \
    Hd_[(q4 + 2) * H2S + u2b] = (u16)p23;                                     \
    Hd_[(q4 + 3) * H2S + u2b] = (u16)(p23 >> 16);                             \
  } } while (0)

#define L1_STEP(PAR, SLOT, XRP)                                               \
  do { if (isL1) {                                                            \
    const u16* Xc_ = X1[(PAR)];                                               \
    u16* Xn_ = X1[(PAR) ^ 1];                                                 \
    f32x4 a0 = (f32x4){br[0], br[0], br[0], br[0]};                           \
    f32x4 a1 = (f32x4){br[1], br[1], br[1], br[1]};                           \
    f32x4 a2 = (f32x4){br[2], br[2], br[2], br[2]};                           \
    f32x4 a3 = (f32x4){br[3], br[3], br[3], br[3]};                           \
    __builtin_amdgcn_s_setprio(1);                                            \
    _Pragma("unroll") for (int kc = 0; kc < 4; kc++) {                        \
      const short8 ah = *(const short8*)&Xc_[cX1 + kc * 32 + q8];             \
      a0 = mfma_(ah, wu[0 * 4 + kc], a0);                                     \
      a1 = mfma_(ah, wu[1 * 4 + kc], a1);                                     \
      a2 = mfma_(ah, wu[2 * 4 + kc], a2);                                     \
      a3 = mfma_(ah, wu[3 * 4 + kc], a3);                                     \
    }                                                                         \
    {                                                                         \
      const short8 ax = *(const short8*)&(XRP)[cXC + (SLOT) * 40 + q8];       \
      a0 = mfma_(ax, *(const short8*)&W1xF[(0 * 8 + wv) * 512 + l8], a0);     \
      a1 = mfma_(ax, *(const short8*)&W1xF[(1 * 8 + wv) * 512 + l8], a1);     \
      a2 = mfma_(ax, *(const short8*)&W1xF[(2 * 8 + wv) * 512 + l8], a2);     \
      a3 = mfma_(ax, *(const short8*)&W1xF[(3 * 8 + wv) * 512 + l8], a3);     \
    }                                                                         \
    __builtin_amdgcn_s_setprio(0);                                            \
    const float h0_ = cellr(a0[0], a1[0], a2[0], a3[0], cs0);                 \
    const float h1_ = cellr(a0[1], a1[1], a2[1], a3[1], cs1);                 \
    const float h2_ = cellr(a0[2], a1[2], a2[2], a3[2], cs2);                 \
    const float h3_ = cellr(a0[3], a1[3], a2[3], a3[3], cs3);                 \
    const u32 p01 = pkbf(h0_, h1_), p23 = pkbf(h2_, h3_);                     \
    Xn_[(q4 + 0) * X1S + u2] = (u16)p01;                                      \
    Xn_[(q4 + 1) * X1S + u2] = (u16)(p01 >> 16);                              \
    Xn_[(q4 + 2) * X1S + u2] = (u16)p23;                                      \
    Xn_[(q4 + 3) * X1S + u2] = (u16)(p23 >> 16);                              \
  } } while (0)

  // ---- encoder: 25 chunks x 8 unrolled steps (t = 8m + j, parity = j&1) ----
  #pragma unroll 1
  for (int m = 0; m < 25; ++m) {
    const u16* xr = XCH[m & 1];
    u16* xw = XCH[(m & 1) ^ 1];

    // j = 0: issue next-chunk loads early (hide HBM under L2 MFMAs)
    float4v stg0, stg1;
    const bool doLd = isL2 && (m < 24);
    const int i0 = tid - 512;
    const int r0 = i0 >> 5, rem0 = i0 & 31, st0 = rem0 >> 2, hf0 = rem0 & 3;
    const int i1 = i0 + 256;
    const int r1 = i1 >> 5, rem1 = i1 & 31, st1 = rem1 >> 2, hf1 = rem1 & 3;
    if (doLd) {
      const int t0 = (m + 1) << 3;
      stg0 = *(const float4v*)&xh[(bb + r0) * 3200 + (t0 + st0) * 16 + hf0 * 4];
      stg1 = *(const float4v*)&xh[(bb + r1) * 3200 + (t0 + st1) * 16 + hf1 * 4];
    }
    if (m) L2_STEP(0);
    if (doLd) {
      *(uint2v*)&xw[r0 * XCS + st0 * 40 + hf0 * 4] =
          (uint2v){pkbf(stg0[0], stg0[1]), pkbf(stg0[2], stg0[3])};
      *(uint2v*)&xw[r1 * XCS + st1 * 40 + hf1 * 4] =
          (uint2v){pkbf(stg1[0], stg1[1]), pkbf(stg1[2], stg1[3])};
    } else if (isL2 && m == 24) {                     // decoder chunk 25 (xfr)
      for (int e = i0; e < 16 * 8 * 14; e += 256) {
        const int r = e / 112, rem2 = e % 112, st = rem2 / 14, f = rem2 % 14;
        xw[r * XCS + st * 40 + f] = f2bf(xfr[(bb + r) * 280 + st * 14 + f]);
      }
      if (i0 < 32) {                                  // s=0 feats 14,15
        const int r = i0 >> 1, f = 14 + (i0 & 1);
        xw[r * XCS + f] = f2bf(xh[(bb + r) * 3200 + 199 * 16 + f]);
      }
    }
    L1_STEP(0, 0, xr);
    __syncthreads();

    L2_STEP(1); L1_STEP(1, 1, xr); __syncthreads();
    L2_STEP(0); L1_STEP(0, 2, xr); __syncthreads();
    L2_STEP(1); L1_STEP(1, 3, xr); __syncthreads();
    L2_STEP(0); L1_STEP(0, 4, xr); __syncthreads();
    L2_STEP(1); L1_STEP(1, 5, xr); __syncthreads();
    L2_STEP(0); L1_STEP(0, 6, xr); __syncthreads();
    L2_STEP(1); L1_STEP(1, 7, xr); __syncthreads();
  }

  // ---- t = 200 (first decoder input, no head yet) + load chunk 26 ----
  {
    L2_STEP(0);
    if (isL2) {                                       // chunk 26 -> XCH[0]
      u16* dst = (u16*)XCH[0];
      const int i0 = tid - 512;
      for (int e = i0; e < 16 * 8 * 14; e += 256) {
        const int r = e / 112, rem2 = e % 112, st = rem2 / 14, f = rem2 % 14;
        dst[r * XCS + st * 40 + f] = f2bf(xfr[(bb + r) * 280 + (8 + st) * 14 + f]);
      }
    }
    L1_STEP(0, 0, XCH[1]);
    __syncthreads();
  }

  // ---- decoder: t = 201..220 (cold path, rolled) ----
  #pragma unroll 1
  for (int t = 201; t <= 220; ++t) {
    L2_STEP(t & 1);
    if (isL2 && t == 208) {                           // chunk 27 -> XCH[1]
      u16* dst = (u16*)XCH[1];
      const int i0 = tid - 512;
      for (int e = i0; e < 16 * 8 * 14; e += 256) {
        const int r = e / 112, rem2 = e % 112, st = rem2 / 14, f = rem2 % 14;
        if (16 + st < 20)
          dst[r * XCS + st * 40 + f] = f2bf(xfr[(bb + r) * 280 + (16 + st) * 14 + f]);
      }
    }
    __syncthreads();                                  // #1: h2(t-1) visible
    if (wv == 8) {
      u16* Hd_ = H2B[(t & 1) ^ 1];
      f32x4 d0 = (f32x4){bdr0, bdr0, bdr0, bdr0};
      f32x4 d1 = (f32x4){bdr1, bdr1, bdr1, bdr1};
      #pragma unroll
      for (int kc = 0; kc < 2; kc++) {
        const short8 ad = *(const short8*)&Hd_[cH2 + kc * 32 + q8];
        d0 = mfma_(ad, *(const short8*)&WdF[(0 + kc) * 512 + l8], d0);
        d1 = mfma_(ad, *(const short8*)&WdF[(2 + kc) * 512 + l8], d1);
      }
      #pragma unroll
      for (int r = 0; r < 4; r++) {
        DB[(q4 + r) * DBS + c]      = f2bf(fmaxf(d0[r], 0.f));
        DB[(q4 + r) * DBS + 16 + c] = f2bf(fmaxf(d1[r], 0.f));
      }
      // same-wave write->read: compiler inserts lgkmcnt
      const short8 ap  = *(const short8*)&DB[c * DBS + q8];
      const short8 wfv = *(const short8*)&WfF[l8];
      f32x4 accp = (f32x4){bfr, bfr, bfr, bfr};
      accp = mfma_(ap, wfv, accp);
      if (c < 2) {
        u16* slot = &XCH[(t >> 3) & 1][0];
        #pragma unroll
        for (int r = 0; r < 4; r++) {
          const int b = q4 + r;
          out[(bb + b) * 40 + (t - 201) * 2 + c] = accp[r];
          slot[b * XCS + (t & 7) * 40 + 14 + c] = f2bf(accp[r]);  // pred -> x(t)
        }
      }
    }
    __syncthreads();                                  // #2: pred in XCH visible
    if (t <= 219) L1_STEP(t & 1, t & 7, XCH[(t >> 3) & 1]);
    __syncthreads();                                  // end of step
  }
}

extern "C" void kernel_launch(void* const* d_in, const int* in_sizes, int n_in,
                              void* d_out, int out_size, void* d_ws, size_t ws_size,
                              hipStream_t stream) {
  (void)in_sizes; (void)n_in; (void)out_size; (void)d_ws; (void)ws_size;
  spc_lstm<<<dim3(256), dim3(768), 0, stream>>>(
      (const float*)d_in[0],  (const float*)d_in[1],
      (const float*)d_in[2],  (const float*)d_in[3],
      (const float*)d_in[4],  (const float*)d_in[5],
      (const float*)d_in[6],  (const float*)d_in[7],
      (const float*)d_in[8],  (const float*)d_in[9],
      (const float*)d_in[10], (const float*)d_in[11],
      (const float*)d_in[12], (const float*)d_in[13],
      (const float*)d_in[14], (float*)d_out);
}

// Round 22
// 404.099 us; speedup vs baseline: 1.0728x; 1.0069x over previous
//
#include <hip/hip_runtime.h>

typedef unsigned short u16;
typedef unsigned int u32;

using short8  = __attribute__((ext_vector_type(8))) short;
using f32x4   = __attribute__((ext_vector_type(4))) float;
using float4v = __attribute__((ext_vector_type(4))) float;
using uint2v  = __attribute__((ext_vector_type(2))) unsigned int;

#define LOG2E 1.44269504088896340736f

// X1 row (per batch): [h1 0:128 | pad] (u16)
#define X1S 136
// H2 row: [h2 0:64 | pad]
#define H2S 72
#define DBS 40
// XCH row stride: 8 steps * 40 + 8 pad (656 B: 16B-aligned, bank-stride 4)
#define XCS 328

__device__ __forceinline__ u16 f2bf(float f) {
  u32 u = __float_as_uint(f);
  return (u16)((u + 0x7FFFu + ((u >> 16) & 1u)) >> 16);
}
// packed f32x2 -> bf16x2, RNE (same rounding as f2bf), 1 instr
__device__ __forceinline__ u32 pkbf(float a, float b) {
  u32 r;
  asm("v_cvt_pk_bf16_f32 %0, %1, %2" : "=v"(r) : "v"(a), "v"(b));
  return r;
}
// R22 cell: 8 trans (5 exp + 3 rcp) vs R20's 10. R21's 7-trans version
// FAILED (absmax 1.17e-2): routing carried state cr through the shared
// fraction (cr*ei1*gp1 / den) injected compounding rounding into c over
// 220 steps. Fix: sigma(f)*cr kept EXACT as R20 (rcp(1+Ef), fma into cr);
// fuse only the NON-carried products:
//   it = sigma(i)*tanh(g) = (G-1)*rcp((1+Ei)(G+1))
//   hn = sigma(o)*tanh(cn) = (Ec-1)*rcp((1+Eo)(Ec+1))
// Their rearrangement error (~1e-7) is additive-injection only, far below
// the bf16 quantum (~4e-3) that dominates h anyway.
__device__ __forceinline__ float cellr(float gi, float gf, float gg, float go, float& cr) {
  const float Ei = __builtin_amdgcn_exp2f(-LOG2E * gi);        // e^-i
  const float G  = __builtin_amdgcn_exp2f(2.0f * LOG2E * gg);  // e^{2g}
  const float it = (G - 1.0f) *
      __builtin_amdgcn_rcpf((1.0f + Ei) * (G + 1.0f));         // sig(i)*tanh(g)
  const float fg = __builtin_amdgcn_rcpf(
      1.0f + __builtin_amdgcn_exp2f(-LOG2E * gf));             // sig(f), exact
  const float cn = fg * cr + it;
  const float Ec = __builtin_amdgcn_exp2f(2.0f * LOG2E * cn);  // e^{2cn}
  const float Eo = __builtin_amdgcn_exp2f(-LOG2E * go);        // e^-o
  const float hn = (Ec - 1.0f) *
      __builtin_amdgcn_rcpf((1.0f + Eo) * (Ec + 1.0f));        // sig(o)*tanh(cn)
  cr = cn;
  return hn;
}
__device__ __forceinline__ f32x4 mfma_(short8 a, short8 b, f32x4 c) {
  return __builtin_amdgcn_mfma_f32_16x16x32_bf16(a, b, c, 0, 0, 0);
}

// R22 = R20 (360us, WRITE 2.9MB, VGPR 84) + safe 8-trans cell (above).
// R20 recap: wu[16] exact-fit overlay (L1 Whh1; L2 Whh2 + Wih2 kc0,1),
// halved W2F (kc2,3), W1xF in LDS; per-step LDS reads 128 b128.
__global__ __launch_bounds__(768, 3) void spc_lstm(
    const float* __restrict__ xh,   const float* __restrict__ xfr,
    const float* __restrict__ Wih1, const float* __restrict__ Whh1,
    const float* __restrict__ bih1, const float* __restrict__ bhh1,
    const float* __restrict__ Wih2, const float* __restrict__ Whh2,
    const float* __restrict__ bih2, const float* __restrict__ bhh2,
    const float* __restrict__ Wd,   const float* __restrict__ bd,
    const float* __restrict__ Wf,   const float* __restrict__ bfv,
    const float* __restrict__ ob,   float* __restrict__ out)
{
  __shared__ __align__(16) u16 X1[2][16 * X1S];   //  8704 B
  __shared__ __align__(16) u16 H2B[2][16 * H2S];  //  4608 B
  __shared__ __align__(16) u16 DB[16 * DBS];      //  1280 B
  __shared__ __align__(16) u16 W1xF[32 * 512];    // 32768 B (zeros k>=16 baked)
  __shared__ __align__(16) u16 W2F[32 * 512];     // 32768 B (Wih2 kc=2,3 only)
  __shared__ __align__(16) u16 WdF[4 * 512];      //  4096 B
  __shared__ __align__(16) u16 WfF[512];          //  1024 B
  __shared__ __align__(16) u16 XCH[2][16 * XCS];  // 20992 B x chunk ring
  // total ~106 KB

  const int tid = threadIdx.x;
  const int wv  = tid >> 6;          // 0..11
  const int l   = tid & 63;
  const int c   = l & 15;
  const int q   = l >> 4;
  const int bb  = blockIdx.x << 4;
  const bool isL1 = (wv < 8);
  const bool isL2 = !isL1;
  const int  wv8  = wv - 8;

  // hoisted lane-offsets (u16 indices)
  const int cX1 = c * X1S, cH2 = c * H2S, cXC = c * XCS;
  const int l8 = l * 8, q8 = q * 8, q4 = q * 4;
  const int u2  = wv * 16 + c;       // L1 unit col
  const int u2b = wv8 * 16 + c;      // L2 unit col
  const int w2o = wv8 * 8;           // W2F tile base (halved layout)

  // Role-overlaid persistent weight registers (64 VGPR, fits at cap 84):
  //  L1: wu[ty*4+kc]=Whh1
  //  L2: wu[ty*2+kc]=Whh2 (0..7), wu[8+ty*2+kc]=Wih2 kc0,1 (8..15)
  short8 wu[16];
  float  br[4];
  float  cs0 = 0.f, cs1 = 0.f, cs2 = 0.f, cs3 = 0.f;

  // ---- zero activation + chunk LDS ----
  for (int i = tid; i < 2 * 16 * X1S; i += 768) ((u16*)X1)[i] = 0;
  for (int i = tid; i < 2 * 16 * H2S; i += 768) ((u16*)H2B)[i] = 0;
  for (int i = tid; i < 16 * DBS; i += 768) DB[i] = 0;
  for (int i = tid; i < 2 * 16 * XCS; i += 768) ((u16*)XCH)[i] = 0;
  __syncthreads();

  // ---- weight LDS fills (fragment-linear: (k,n) -> ((k>>3)*16+n)*8 + (k&7)) ----
  for (int i = tid; i < 32 * 512; i += 768) {         // Wih1 x-frags FULL (zeros k>=16)
    const int T = i >> 9, e = i & 511, k = e >> 4, n = e & 15;
    const int ty = T >> 3, uv = T & 7;
    const int g = ty * 128 + uv * 16 + n;
    W1xF[T * 512 + ((k >> 3) * 16 + n) * 8 + (k & 7)] =
        (k < 16) ? f2bf(Wih1[g * 16 + k]) : (u16)0;
  }
  for (int i = tid; i < 32 * 512; i += 768) {         // Wih2 kc=2,3 tiles
    const int rid = i >> 9, e = i & 511, k = e >> 4, n = e & 15;
    const int ww = rid >> 3, ty = (rid >> 1) & 3, kch = rid & 1;
    const int g = ty * 64 + ww * 16 + n;
    W2F[rid * 512 + ((k >> 3) * 16 + n) * 8 + (k & 7)] =
        f2bf(Wih2[g * 128 + (2 + kch) * 32 + k]);
  }
  for (int i = tid; i < 4 * 512; i += 768) {          // Wd tiles (ww, kc2)
    const int tix = i >> 9, e = i & 511, k = e >> 4, n = e & 15;
    const int ww = tix >> 1, kc2 = tix & 1;
    WdF[tix * 512 + ((k >> 3) * 16 + n) * 8 + (k & 7)] =
        f2bf(Wd[(ww * 16 + n) * 64 + kc2 * 32 + k]);
  }
  {                                                   // Wf (zeros n>=2)
    const int k = tid >> 4, n = tid & 15;
    if (tid < 512)
      WfF[((k >> 3) * 16 + n) * 8 + (k & 7)] = (n < 2) ? f2bf(Wf[n * 32 + k]) : (u16)0;
  }

  // ---- chunk 0 load (L2 waves): steps 0-7 into XCH[0] ----
  if (isL2) {
    const int i0 = tid - 512;
    #pragma unroll
    for (int p = 0; p < 2; p++) {
      const int idx = i0 + p * 256;
      const int r = idx >> 5, rem = idx & 31, st = rem >> 2, hf = rem & 3;
      const float4v v = *(const float4v*)&xh[(bb + r) * 3200 + st * 16 + hf * 4];
      *(uint2v*)&XCH[0][r * XCS + st * 40 + hf * 4] =
          (uint2v){pkbf(v[0], v[1]), pkbf(v[2], v[3])};
    }
  }

  // ---- register weights / biases (role-overlaid) ----
  if (isL1) {
    #pragma unroll
    for (int ty = 0; ty < 4; ty++) {
      const int g = ty * 128 + wv * 16 + c;
      br[ty] = bih1[g] + bhh1[g];
      #pragma unroll
      for (int kc = 0; kc < 4; kc++) {
        short8 v;
        #pragma unroll
        for (int j = 0; j < 8; j++)
          v[j] = (short)f2bf(Whh1[g * 128 + kc * 32 + q * 8 + j]);
        wu[ty * 4 + kc] = v;
      }
    }
  } else {
    #pragma unroll
    for (int ty = 0; ty < 4; ty++) {
      const int g2 = ty * 64 + wv8 * 16 + c;
      br[ty] = bih2[g2] + bhh2[g2];
      #pragma unroll
      for (int kc = 0; kc < 2; kc++) {                // Whh2 frags -> wu[0..7]
        short8 v;
        #pragma unroll
        for (int j = 0; j < 8; j++)
          v[j] = (short)f2bf(Whh2[g2 * 64 + kc * 32 + q * 8 + j]);
        wu[ty * 2 + kc] = v;
      }
      #pragma unroll
      for (int kc = 0; kc < 2; kc++) {                // Wih2 kc0,1 -> wu[8..15]
        short8 v;
        #pragma unroll
        for (int j = 0; j < 8; j++)
          v[j] = (short)f2bf(Wih2[g2 * 128 + kc * 32 + q * 8 + j]);
        wu[8 + ty * 2 + kc] = v;
      }
    }
  }
  float bdr0 = 0.f, bdr1 = 0.f, bfr = 0.f;
  if (wv == 8) {
    bdr0 = bd[c];
    bdr1 = bd[16 + c];
    if (c < 2) bfr = bfv[c] + ob[c];
  }
  __syncthreads();

// ---- step macros (PAR/SLOT may be constants (hot) or runtime (decoder)) ----
#define L2_STEP(PAR)                                                          \
  do { if (isL2) {                                                            \
    const u16* Xc_ = X1[(PAR)];                                               \
    const u16* Hp_ = H2B[(PAR)];                                              \
    u16* Hd_ = H2B[(PAR) ^ 1];                                                \
    f32x4 a0 = (f32x4){br[0], br[0], br[0], br[0]};                           \
    f32x4 a1 = (f32x4){br[1], br[1], br[1], br[1]};                           \
    f32x4 a2 = (f32x4){br[2], br[2], br[2], br[2]};                           \
    f32x4 a3 = (f32x4){br[3], br[3], br[3], br[3]};                           \
    __builtin_amdgcn_s_setprio(1);                                            \
    _Pragma("unroll") for (int kc = 0; kc < 2; kc++) {                        \
      const short8 fh = *(const short8*)&Xc_[cX1 + kc * 32 + q8];             \
      a0 = mfma_(fh, wu[8 + 0 * 2 + kc], a0);                                 \
      a1 = mfma_(fh, wu[8 + 1 * 2 + kc], a1);                                 \
      a2 = mfma_(fh, wu[8 + 2 * 2 + kc], a2);                                 \
      a3 = mfma_(fh, wu[8 + 3 * 2 + kc], a3);                                 \
    }                                                                         \
    _Pragma("unroll") for (int kc = 2; kc < 4; kc++) {                        \
      const short8 fh = *(const short8*)&Xc_[cX1 + kc * 32 + q8];             \
      const int kh = kc - 2;                                                  \
      a0 = mfma_(fh, *(const short8*)&W2F[(w2o + 0 * 2 + kh) * 512 + l8], a0);\
      a1 = mfma_(fh, *(const short8*)&W2F[(w2o + 1 * 2 + kh) * 512 + l8], a1);\
      a2 = mfma_(fh, *(const short8*)&W2F[(w2o + 2 * 2 + kh) * 512 + l8], a2);\
      a3 = mfma_(fh, *(const short8*)&W2F[(w2o + 3 * 2 + kh) * 512 + l8], a3);\
    }                                                                         \
    _Pragma("unroll") for (int kc = 0; kc < 2; kc++) {                        \
      const short8 hh = *(const short8*)&Hp_[cH2 + kc * 32 + q8];             \
      a0 = mfma_(hh, wu[0 * 2 + kc], a0);                                     \
      a1 = mfma_(hh, wu[1 * 2 + kc], a1);                                     \
      a2 = mfma_(hh, wu[2 * 2 + kc], a2);                                     \
      a3 = mfma_(hh, wu[3 * 2 + kc], a3);                                     \
    }                                                                         \
    __builtin_amdgcn_s_setprio(0);                                            \
    const float h0_ = cellr(a0[0], a1[0], a2[0], a3[0], cs0);                 \
    const float h1_ = cellr(a0[1], a1[1], a2[1], a3[1], cs1);                 \
    const float h2_ = cellr(a0[2], a1[2], a2[2], a3[2], cs2);                 \
    const float h3_ = cellr(a0[3], a1[3], a2[3], a3[3], cs3);                 \
    const u32 p01 = pkbf(h0_, h1_), p23 = pkbf(h2_, h3_);                     \
    Hd_[(q4 + 0) * H2S + u2b] = (u16)p01;                                     \
    Hd_[(q4 + 1) * H2S + u2b] = (u16)(p01 >> 16);                             \
    Hd_[(q4 + 2) * H2S + u2b] = (u16)p23;                                     \
    Hd_[(q4 + 3) * H2S + u2b] = (u16)(p23 >> 16);                             \
  } } while (0)

#define L1_STEP(PAR, SLOT, XRP)                                               \
  do { if (isL1) {                                                            \
    const u16* Xc_ = X1[(PAR)];                                               \
    u16* Xn_ = X1[(PAR) ^ 1];                                                 \
    f32x4 a0 = (f32x4){br[0], br[0], br[0], br[0]};                           \
    f32x4 a1 = (f32x4){br[1], br[1], br[1], br[1]};                           \
    f32x4 a2 = (f32x4){br[2], br[2], br[2], br[2]};                           \
    f32x4 a3 = (f32x4){br[3], br[3], br[3], br[3]};                           \
    __builtin_amdgcn_s_setprio(1);                                            \
    _Pragma("unroll") for (int kc = 0; kc < 4; kc++) {                        \
      const short8 ah = *(const short8*)&Xc_[cX1 + kc * 32 + q8];             \
      a0 = mfma_(ah, wu[0 * 4 + kc], a0);                                     \
      a1 = mfma_(ah, wu[1 * 4 + kc], a1);                                     \
      a2 = mfma_(ah, wu[2 * 4 + kc], a2);                                     \
      a3 = mfma_(ah, wu[3 * 4 + kc], a3);                                     \
    }                                                                         \
    {                                                                         \
      const short8 ax = *(const short8*)&(XRP)[cXC + (SLOT) * 40 + q8];       \
      a0 = mfma_(ax, *(const short8*)&W1xF[(0 * 8 + wv) * 512 + l8], a0);     \
      a1 = mfma_(ax, *(const short8*)&W1xF[(1 * 8 + wv) * 512 + l8], a1);     \
      a2 = mfma_(ax, *(const short8*)&W1xF[(2 * 8 + wv) * 512 + l8], a2);     \
      a3 = mfma_(ax, *(const short8*)&W1xF[(3 * 8 + wv) * 512 + l8], a3);     \
    }                                                                         \
    __builtin_amdgcn_s_setprio(0);                                            \
    const float h0_ = cellr(a0[0], a1[0], a2[0], a3[0], cs0);                 \
    const float h1_ = cellr(a0[1], a1[1], a2[1], a3[1], cs1);                 \
    const float h2_ = cellr(a0[2], a1[2], a2[2], a3[2], cs2);                 \
    const float h3_ = cellr(a0[3], a1[3], a2[3], a3[3], cs3);                 \
    const u32 p01 = pkbf(h0_, h1_), p23 = pkbf(h2_, h3_);                     \
    Xn_[(q4 + 0) * X1S + u2] = (u16)p01;                                      \
    Xn_[(q4 + 1) * X1S + u2] = (u16)(p01 >> 16);                              \
    Xn_[(q4 + 2) * X1S + u2] = (u16)p23;                                      \
    Xn_[(q4 + 3) * X1S + u2] = (u16)(p23 >> 16);                              \
  } } while (0)

  // ---- encoder: 25 chunks x 8 unrolled steps (t = 8m + j, parity = j&1) ----
  #pragma unroll 1
  for (int m = 0; m < 25; ++m) {
    const u16* xr = XCH[m & 1];
    u16* xw = XCH[(m & 1) ^ 1];

    // j = 0: issue next-chunk loads early (hide HBM under L2 MFMAs)
    float4v stg0, stg1;
    const bool doLd = isL2 && (m < 24);
    const int i0 = tid - 512;
    const int r0 = i0 >> 5, rem0 = i0 & 31, st0 = rem0 >> 2, hf0 = rem0 & 3;
    const int i1 = i0 + 256;
    const int r1 = i1 >> 5, rem1 = i1 & 31, st1 = rem1 >> 2, hf1 = rem1 & 3;
    if (doLd) {
      const int t0 = (m + 1) << 3;
      stg0 = *(const float4v*)&xh[(bb + r0) * 3200 + (t0 + st0) * 16 + hf0 * 4];
      stg1 = *(const float4v*)&xh[(bb + r1) * 3200 + (t0 + st1) * 16 + hf1 * 4];
    }
    if (m) L2_STEP(0);
    if (doLd) {
      *(uint2v*)&xw[r0 * XCS + st0 * 40 + hf0 * 4] =
          (uint2v){pkbf(stg0[0], stg0[1]), pkbf(stg0[2], stg0[3])};
      *(uint2v*)&xw[r1 * XCS + st1 * 40 + hf1 * 4] =
          (uint2v){pkbf(stg1[0], stg1[1]), pkbf(stg1[2], stg1[3])};
    } else if (isL2 && m == 24) {                     // decoder chunk 25 (xfr)
      for (int e = i0; e < 16 * 8 * 14; e += 256) {
        const int r = e / 112, rem2 = e % 112, st = rem2 / 14, f = rem2 % 14;
        xw[r * XCS + st * 40 + f] = f2bf(xfr[(bb + r) * 280 + st * 14 + f]);
      }
      if (i0 < 32) {                                  // s=0 feats 14,15
        const int r = i0 >> 1, f = 14 + (i0 & 1);
        xw[r * XCS + f] = f2bf(xh[(bb + r) * 3200 + 199 * 16 + f]);
      }
    }
    L1_STEP(0, 0, xr);
    __syncthreads();

    L2_STEP(1); L1_STEP(1, 1, xr); __syncthreads();
    L2_STEP(0); L1_STEP(0, 2, xr); __syncthreads();
    L2_STEP(1); L1_STEP(1, 3, xr); __syncthreads();
    L2_STEP(0); L1_STEP(0, 4, xr); __syncthreads();
    L2_STEP(1); L1_STEP(1, 5, xr); __syncthreads();
    L2_STEP(0); L1_STEP(0, 6, xr); __syncthreads();
    L2_STEP(1); L1_STEP(1, 7, xr); __syncthreads();
  }

  // ---- t = 200 (first decoder input, no head yet) + load chunk 26 ----
  {
    L2_STEP(0);
    if (isL2) {                                       // chunk 26 -> XCH[0]
      u16* dst = (u16*)XCH[0];
      const int i0 = tid - 512;
      for (int e = i0; e < 16 * 8 * 14; e += 256) {
        const int r = e / 112, rem2 = e % 112, st = rem2 / 14, f = rem2 % 14;
        dst[r * XCS + st * 40 + f] = f2bf(xfr[(bb + r) * 280 + (8 + st) * 14 + f]);
      }
    }
    L1_STEP(0, 0, XCH[1]);
    __syncthreads();
  }

  // ---- decoder: t = 201..220 (cold path, rolled) ----
  #pragma unroll 1
  for (int t = 201; t <= 220; ++t) {
    L2_STEP(t & 1);
    if (isL2 && t == 208) {                           // chunk 27 -> XCH[1]
      u16* dst = (u16*)XCH[1];
      const int i0 = tid - 512;
      for (int e = i0; e < 16 * 8 * 14; e += 256) {
        const int r = e / 112, rem2 = e % 112, st = rem2 / 14, f = rem2 % 14;
        if (16 + st < 20)
          dst[r * XCS + st * 40 + f] = f2bf(xfr[(bb + r) * 280 + (16 + st) * 14 + f]);
      }
    }
    __syncthreads();                                  // #1: h2(t-1) visible
    if (wv == 8) {
      u16* Hd_ = H2B[(t & 1) ^ 1];
      f32x4 d0 = (f32x4){bdr0, bdr0, bdr0, bdr0};
      f32x4 d1 = (f32x4){bdr1, bdr1, bdr1, bdr1};
      #pragma unroll
      for (int kc = 0; kc < 2; kc++) {
        const short8 ad = *(const short8*)&Hd_[cH2 + kc * 32 + q8];
        d0 = mfma_(ad, *(const short8*)&WdF[(0 + kc) * 512 + l8], d0);
        d1 = mfma_(ad, *(const short8*)&WdF[(2 + kc) * 512 + l8], d1);
      }
      #pragma unroll
      for (int r = 0; r < 4; r++) {
        DB[(q4 + r) * DBS + c]      = f2bf(fmaxf(d0[r], 0.f));
        DB[(q4 + r) * DBS + 16 + c] = f2bf(fmaxf(d1[r], 0.f));
      }
      // same-wave write->read: compiler inserts lgkmcnt
      const short8 ap  = *(const short8*)&DB[c * DBS + q8];
      const short8 wfv = *(const short8*)&WfF[l8];
      f32x4 accp = (f32x4){bfr, bfr, bfr, bfr};
      accp = mfma_(ap, wfv, accp);
      if (c < 2) {
        u16* slot = &XCH[(t >> 3) & 1][0];
        #pragma unroll
        for (int r = 0; r < 4; r++) {
          const int b = q4 + r;
          out[(bb + b) * 40 + (t - 201) * 2 + c] = accp[r];
          slot[b * XCS + (t & 7) * 40 + 14 + c] = f2bf(accp[r]);  // pred -> x(t)
        }
      }
    }
    __syncthreads();                                  // #2: pred in XCH visible
    if (t <= 219) L1_STEP(t & 1, t & 7, XCH[(t >> 3) & 1]);
    __syncthreads();                                  // end of step
  }
}

extern "C" void kernel_launch(void* const* d_in, const int* in_sizes, int n_in,
                              void* d_out, int out_size, void* d_ws, size_t ws_size,
                              hipStream_t stream) {
  (void)in_sizes; (void)n_in; (void)out_size; (void)d_ws; (void)ws_size;
  spc_lstm<<<dim3(256), dim3(768), 0, stream>>>(
      (const float*)d_in[0],  (const float*)d_in[1],
      (const float*)d_in[2],  (const float*)d_in[3],
      (const float*)d_in[4],  (const float*)d_in[5],
      (const float*)d_in[6],  (const float*)d_in[7],
      (const float*)d_in[8],  (const float*)d_in[9],
      (const float*)d_in[10], (const float*)d_in[11],
      (const float*)d_in[12], (const float*)d_in[13],
      (const float*)d_in[14], (float*)d_out);
}